// Round 16
// baseline (172.510 us; speedup 1.0000x reference)
//
#include <hip/hip_runtime.h>
#include <cstdint>
#include <cstddef>

typedef unsigned short u16;
typedef unsigned int u32;
typedef __attribute__((ext_vector_type(4))) float f32x4;
typedef __attribute__((ext_vector_type(4))) float float4v;
typedef __attribute__((ext_vector_type(8))) short short8;

#define LDC 4368   // fused GEMM output row stride (cols: qkv 0..3071 | w1 3072 | w2 3136 | r1 3200 | r2 3264 | mem_val 3328..4351 | gate 4352..4367)

__device__ __forceinline__ float bf2f(u16 u){ return __uint_as_float(((u32)u) << 16); }
__device__ __forceinline__ u16 f2bf(float f){
  u32 x = __float_as_uint(f);
  x += 0x7FFFu + ((x >> 16) & 1u);   // RNE
  return (u16)(x >> 16);
}
__device__ __forceinline__ u16 f2bf_rhu(float f){          // round-half-up (cheap, for P>=0)
  return (u16)((__float_as_uint(f) + 0x8000u) >> 16);
}
#if __has_builtin(__builtin_amdgcn_exp2f)
#define EXP2(x) __builtin_amdgcn_exp2f(x)
#else
#define EXP2(x) exp2f(x)
#endif
__device__ __forceinline__ void mfma16(f32x4& d, short8 a, short8 b){
  d = __builtin_amdgcn_mfma_f32_16x16x32_bf16(a, b, d, 0, 0, 0);
}
__device__ __forceinline__ void async_lds16(void* lds, const void* g){
  __builtin_amdgcn_global_load_lds((const __attribute__((address_space(1))) u32*)g,
                                   (__attribute__((address_space(3))) u32*)lds, 16, 0, 0);
}
__device__ __forceinline__ float sigm(float x){ return 1.f / (1.f + __expf(-x)); }
__device__ __forceinline__ void storev(u16* p, float v){ *p = f2bf(v); }
__device__ __forceinline__ void storev(float* p, float v){ *p = v; }

// ---------------- shared 32x32 convert+transpose helper ----------------
__device__ __forceinline__ void t32(const float* __restrict__ src, u16* __restrict__ dst,
                                    int R, int Ccols, int c0, int r0, int tid, u16 tile[32][33])
{
  int tx = tid & 31, ty0 = tid >> 5;
  #pragma unroll
  for (int i = 0; i < 4; i++){
    int r = r0 + ty0 + i * 8, c = c0 + tx;
    u16 v = 0;
    if (r < R && c < Ccols) v = f2bf(src[(size_t)r * Ccols + c]);
    tile[ty0 + i * 8][tx] = v;
  }
  __syncthreads();
  #pragma unroll
  for (int i = 0; i < 4; i++){
    int cc = c0 + ty0 + i * 8, rr = r0 + tx;
    if (cc < Ccols && rr < R) dst[(size_t)cc * R + rr] = tile[tx][ty0 + i * 8];
  }
}

// ---------------- fused preprocessing: cvt x | bias | all weight transposes ----------------
__global__ __launch_bounds__(256) void prep_kernel(
    const float* __restrict__ x, const float* __restrict__ bqkv, const float* __restrict__ bmv,
    const float* __restrict__ bg, const float* __restrict__ Wqkv,
    const float* __restrict__ W1w, const float* __restrict__ W2w,
    const float* __restrict__ W1r, const float* __restrict__ W2r,
    const float* __restrict__ Wmv, const float* __restrict__ Wout, const float* __restrict__ Wg,
    u16* __restrict__ xb, float* __restrict__ biasfull, u16* __restrict__ BT, u16* __restrict__ WoutT)
{
  __shared__ u16 tile[32][33];
  const int b = blockIdx.x, tid = threadIdx.x;
  if (b < 2048){
    int i = b * 256 + tid;   // 524288 total, exact
    float4v a = *(const float4v*)(x + (size_t)i * 8);
    float4v c = *(const float4v*)(x + (size_t)i * 8 + 4);
    short8 o;
    #pragma unroll
    for (int j = 0; j < 4; j++){ o[j] = (short)f2bf(a[j]); o[4 + j] = (short)f2bf(c[j]); }
    *(short8*)(xb + (size_t)i * 8) = o;
  } else if (b < 2066){
    int i = (b - 2048) * 256 + tid;
    if (i < 4368){
      float v;
      if (i < 3072) v = bqkv[i];
      else if (i < 3328) v = 0.f;
      else if (i < 4352) v = bmv[i - 3328];
      else v = bg[i - 4352];
      biasfull[i] = v;
    }
  } else if (b < 5138){
    int local = b - 2066;
    t32(Wqkv, BT, 1024, 3072, (local % 96) * 32, (local / 96) * 32, tid, tile);
  } else if (b < 5394){
    int local = b - 5138;
    int z = local >> 6, rem = local & 63;
    const float* src = (z == 0) ? W1w : (z == 1) ? W2w : (z == 2) ? W1r : W2r;
    t32(src, BT + (size_t)(3072 + z * 64) * 1024, 1024, 64, (rem & 1) * 32, (rem >> 1) * 32, tid, tile);
  } else if (b < 7442){
    int local = b - 5394;
    int z = local >> 10, rem = local & 1023;
    const float* src = z ? Wout : Wmv;
    u16* dst = z ? WoutT : (BT + (size_t)3328 * 1024);
    t32(src, dst, 1024, 1024, (rem & 31) * 32, (rem >> 5) * 32, tid, tile);
  } else {
    int local = b - 7442;
    t32(Wg, BT + (size_t)4352 * 1024, 1024, 16, 0, local * 32, tid, tile);
  }
}

// ---------------- MFMA GEMM: C(MxN) = A(MxK) * BT(NxK)^T + bias ----------------
// 128x128 tile, BK=32, 4 waves (2x2). Double-buffered LDS (32 KiB total).
// One barrier per K-step; next tile's global_load_lds issued BEFORE compute.
// LDS packs 2 global rows per 128B line; slot = ((r&1)*4 + kchunk) ^ (lrow&7):
// linear DMA dest + inverse-swizzled GLOBAL source + swizzled read (rule #21).
// 1D grid, bijective XCD swizzle (gridDim.x % 8 == 0).
template<typename OT>
__global__ __launch_bounds__(256) void gemm_bt(const u16* __restrict__ Ag, const u16* __restrict__ BTg,
                                               const float* __restrict__ bias, OT* __restrict__ Cg,
                                               int M, int N, int K, int ldc)
{
  __shared__ __align__(16) u16 As[2][128 * 32];   // 8 KiB per buffer
  __shared__ __align__(16) u16 Bs[2][128 * 32];
  const int tid = threadIdx.x, lane = tid & 63, w = tid >> 6;
  const int l15 = lane & 15, l4 = lane >> 4;
  const int qx = gridDim.x >> 3, bid = blockIdx.x;
  const int fid = (bid & 7) * qx + (bid >> 3);
  const int m0 = (fid & 31) * 128, n0 = (fid >> 5) * 128;
  const int wr = w >> 1, wc = w & 1;
  f32x4 acc[4][4] = {};
  const u16* aP[2]; const u16* bP[2];
  #pragma unroll
  for (int j = 0; j < 2; j++){
    int i = w * 128 + j * 64 + lane;
    int lrow = i >> 3, cc = i & 7;
    int sc = cc ^ (lrow & 7);
    int grow = lrow * 2 + (sc >> 2);
    int ka = (sc & 3) * 8;
    aP[j] = Ag + (size_t)(m0 + grow) * K + ka;
    int rb = n0 + grow; if (rb > N - 1) rb = N - 1;
    bP[j] = BTg + (size_t)rb * K + ka;
  }
  const int nk = K >> 5;
  #pragma unroll
  for (int j = 0; j < 2; j++){
    async_lds16((char*)As[0] + w * 2048 + j * 1024, aP[j]);
    async_lds16((char*)Bs[0] + w * 2048 + j * 1024, bP[j]);
  }
  __syncthreads();
  for (int t = 0; t < nk; t++){
    const int cur = t & 1;
    if (t + 1 < nk){
      const int k0 = (t + 1) << 5;
      char* An = (char*)As[cur ^ 1] + w * 2048;
      char* Bn = (char*)Bs[cur ^ 1] + w * 2048;
      #pragma unroll
      for (int j = 0; j < 2; j++){
        async_lds16(An + j * 1024, aP[j] + k0);
        async_lds16(Bn + j * 1024, bP[j] + k0);
      }
    }
    const char* Ab = (const char*)As[cur];
    const char* Bb = (const char*)Bs[cur];
    short8 a[4], b[4];
    #pragma unroll
    for (int mi = 0; mi < 4; mi++){
      int r = wr * 64 + mi * 16 + l15;
      int lrow = r >> 1;
      int slot = (((r & 1) << 2) + l4) ^ (lrow & 7);
      a[mi] = *(const short8*)(Ab + lrow * 128 + slot * 16);
    }
    #pragma unroll
    for (int ni = 0; ni < 4; ni++){
      int r = wc * 64 + ni * 16 + l15;
      int lrow = r >> 1;
      int slot = (((r & 1) << 2) + l4) ^ (lrow & 7);
      b[ni] = *(const short8*)(Bb + lrow * 128 + slot * 16);
    }
    #pragma unroll
    for (int mi = 0; mi < 4; mi++)
      #pragma unroll
      for (int ni = 0; ni < 4; ni++)
        mfma16(acc[mi][ni], a[mi], b[ni]);
    __syncthreads();
  }
  #pragma unroll
  for (int mi = 0; mi < 4; mi++){
    #pragma unroll
    for (int ni = 0; ni < 4; ni++){
      int col = n0 + wc * 64 + ni * 16 + l15;
      if (col < N){
        float bv = bias ? bias[col] : 0.f;
        #pragma unroll
        for (int r = 0; r < 4; r++){
          int row = m0 + wr * 64 + mi * 16 + l4 * 4 + r;
          storev(&Cg[(size_t)row * ldc + col], acc[mi][ni][r] + bv);
        }
      }
    }
  }
}

// ---------------- Plucker lines ----------------
__device__ __forceinline__ void ext6(float* L, const float* p, const float* q){
  L[0] = p[0]*q[1] - p[1]*q[0];
  L[1] = p[0]*q[2] - p[2]*q[0];
  L[2] = p[0]*q[3] - p[3]*q[0];
  L[3] = p[1]*q[2] - p[2]*q[1];
  L[4] = p[1]*q[3] - p[3]*q[1];
  L[5] = p[2]*q[3] - p[3]*q[2];
  float n = sqrtf(L[0]*L[0]+L[1]*L[1]+L[2]*L[2]+L[3]*L[3]+L[4]*L[4]+L[5]*L[5]);
  float inv = 1.f / fmaxf(n, 1e-12f);
  #pragma unroll
  for (int i = 0; i < 6; i++) L[i] *= inv;
}

// ---------------- fused: chunk+inline-lines [0,256) | powers [256,272) | transpose_v [272,4368) ----------------
__global__ __launch_bounds__(256) void chunk_tv_kernel(const u16* __restrict__ C, const float* __restrict__ Ain,
                                                       float* __restrict__ Sb, u16* __restrict__ VT,
                                                       float* __restrict__ rd, float* __restrict__ Jw,
                                                       float* __restrict__ Gk)
{
  __shared__ float Jl[4][384];
  __shared__ float Af[4][36], Ml[4][36], Nl[4][36];
  __shared__ u16 tile[32][33];
  __shared__ float Pw[36], Cur[36];
  const int blk = blockIdx.x, tid = threadIdx.x;
  if (blk < 256){
    const int g = tid >> 6, lt = tid & 63;
    const int task = blk * 4 + g;           // bh*32 + c
    const int c = task & 31, bh = task >> 5, h = bh & 15, b = bh >> 4;
    // ---- inline lines for t = c*64 + lt ----
    {
      const int t = c * 64 + lt;
      size_t m = (size_t)b * 2048 + t;
      float w1[4] = {0.f, 0.f, 0.f, 0.f}, w2[4], r1[4], r2[4];
      if (t > 0){
        const u16* p2 = C + (m - 1) * LDC + 3072 + h * 4;
        #pragma unroll
        for (int i = 0; i < 4; i++) w1[i] = bf2f(p2[i]);
      }
      {
        const u16* p2 = C + m * LDC + 3136 + h * 4;
        #pragma unroll
        for (int i = 0; i < 4; i++) w2[i] = bf2f(p2[i]);
        p2 = C + m * LDC + 3200 + h * 4;
        #pragma unroll
        for (int i = 0; i < 4; i++) r1[i] = bf2f(p2[i]);
        p2 = C + m * LDC + 3264 + h * 4;
        #pragma unroll
        for (int i = 0; i < 4; i++) r2[i] = bf2f(p2[i]);
      }
      float L[6], R[6];
      ext6(L, w1, w2);
      ext6(R, r1, r2);
      size_t o = ((size_t)bh * 2048 + t) * 6;
      #pragma unroll
      for (int i = 0; i < 6; i++) rd[o + i] = R[i];
      float jv[6] = { L[5], -L[4], L[3], L[2], -L[1], L[0] };   // write_lines @ J6
      #pragma unroll
      for (int i = 0; i < 6; i++){ Jw[o + i] = jv[i]; Jl[g][lt * 6 + i] = jv[i]; }
    }
    const int p = lt / 6, q = lt % 6;
    if (lt < 36){ Af[g][lt] = Ain[h * 36 + lt]; Ml[g][lt] = 0.f; }
    __syncthreads();
    float arow[6], acol[6];
    if (lt < 36){
      #pragma unroll
      for (int k = 0; k < 6; k++){ arow[k] = Af[g][p * 6 + k]; acol[k] = Af[g][q * 6 + k]; }
    }
    for (int s = 0; s < 64; s++){
      float n = 0.f;
      if (lt < 36){
        #pragma unroll
        for (int k = 0; k < 6; k++) n += arow[k] * Ml[g][k * 6 + q];
        Nl[g][lt] = n;
      }
      __syncthreads();
      if (lt < 36){
        float m = Jl[g][s * 6 + p] * Jl[g][s * 6 + q];
        #pragma unroll
        for (int k = 0; k < 6; k++) m += Nl[g][p * 6 + k] * acol[k];
        Ml[g][lt] = m;
      }
      __syncthreads();
    }
    if (lt < 36) Sb[((size_t)bh * 32 + c) * 36 + lt] = Ml[g][lt];
  } else if (blk < 272){
    // ---- powers: Gk[h][k] = A^k, k = 0..64 ----
    const int h = blk - 256;
    const int p = tid / 6, q = tid % 6;
    if (tid < 36){
      Pw[tid] = Ain[h * 36 + tid];
      float id = (p == q) ? 1.f : 0.f;
      Cur[tid] = id;
      Gk[(size_t)h * 65 * 36 + tid] = id;
    }
    __syncthreads();
    for (int k = 1; k <= 64; k++){
      float v = 0.f;
      if (tid < 36){
        #pragma unroll
        for (int j = 0; j < 6; j++) v += Cur[p * 6 + j] * Pw[j * 6 + q];
      }
      __syncthreads();
      if (tid < 36){
        Cur[tid] = v;
        Gk[((size_t)h * 65 + k) * 36 + tid] = v;
      }
      __syncthreads();
    }
  } else {
    // ---- transpose_v ----
    int local = blk - 272;
    int bh = local >> 7, rem = local & 127;
    int b = bh >> 4, h = bh & 15;
    const u16* src = C + (size_t)b * 2048 * LDC + 2048 + h * 64;
    int c0 = (rem & 1) * 32, r0 = (rem >> 1) * 32;
    int tx = tid & 31, ty0 = tid >> 5;
    #pragma unroll
    for (int i = 0; i < 4; i++)
      tile[ty0 + i * 8][tx] = src[(size_t)(r0 + ty0 + i * 8) * LDC + c0 + tx];
    __syncthreads();
    u16* dstb = VT + (size_t)bh * 64 * 2048;
    #pragma unroll
    for (int i = 0; i < 4; i++)
      dstb[(size_t)(c0 + ty0 + i * 8) * 2048 + r0 + tx] = tile[tx][ty0 + i * 8];
  }
}

// ---------------- fused score [0,256) + attention [256,1280) ----------------
// Score blocks dispatch FIRST (overlap attn's shadow). attn: K/V LDS
// double-buffered, one barrier per KV-iter, and TWO-TILE-DEEP register
// prefetch (tile j in reg set j&1; at iter i ds_write tile i+1 from set
// (i+1)&1, immediately re-issue that set with tile i+3 -> every load gets
// ~2 compute phases of latency shadow). Loop unrolled x2, named reg sets.
// Q pre-scaled by 0.125*log2(e); defer-max THR=11.5 fast path; T5 setprio.
__global__ __launch_bounds__(256) void attn_score_kernel(const u16* __restrict__ C, const u16* __restrict__ VT,
                                                         u16* __restrict__ seqb,
                                                         const float* __restrict__ rd, const float* __restrict__ Jw,
                                                         const float* __restrict__ Gk, const float* __restrict__ Sb,
                                                         float* __restrict__ score)
{
  __shared__ __align__(16) char smem[40960];
  const int blk = blockIdx.x, tid = threadIdx.x;
  if (blk >= 256){
    char* KsB = smem;                        // [2][64][64] swizzled
    char* VsB = smem + 16384;                // [2][64][64]
    const int abk = blk - 256;
    const int bh = abk & 31, bb = bh >> 4, h = bh & 15;
    const int qblk = 31 - (abk >> 5);
    const int lane = tid & 63, w = tid >> 6;
    const int l15 = lane & 15, l4 = lane >> 4;
    u16* Psw = (u16*)(smem + 32768) + w * 1024;   // per-wave [16][64]
    const int q0 = qblk * 64 + w * 16;
    const float csc = 0.1803368801f;   // 0.125 * log2(e)
    const u16* qb = C + (size_t)(bb * 2048 + q0 + l15) * LDC + h * 64 + l4 * 8;
    short8 qf0 = *(const short8*)qb;
    short8 qf1 = *(const short8*)(qb + 32);
    #pragma unroll
    for (int j = 0; j < 8; j++){
      qf0[j] = (short)f2bf(bf2f((u16)qf0[j]) * csc);
      qf1[j] = (short)f2bf(bf2f((u16)qf1[j]) * csc);
    }
    f32x4 o[4] = {};
    float mrun[4], lsum[4];
    #pragma unroll
    for (int r = 0; r < 4; r++){ mrun[r] = -1e30f; lsum[r] = 0.f; }
    const int nkv = qblk + 1;
    const int rowA = tid >> 3, chA = tid & 7;
    const int swA = chA ^ (rowA & 7);
    const u16* Kg = C + (size_t)(bb * 2048) * LDC + 1024 + h * 64 + chA * 8;
    const u16* Vg = VT + ((size_t)bh * 64 + rowA) * 2048 + chA * 8;

    auto stage_regs = [&](int t, short8& k0, short8& k1, short8& v0, short8& v1){
      const int nx = t * 64;
      k0 = *(const short8*)(Kg + (size_t)(nx + rowA) * LDC);
      k1 = *(const short8*)(Kg + (size_t)(nx + rowA + 32) * LDC);
      v0 = *(const short8*)(Vg + nx);
      v1 = *(const short8*)(Vg + nx + 32 * 2048);
    };
    auto lds_write = [&](char* Kd, char* Vd, short8 k0, short8 k1, short8 v0, short8 v1){
      *(short8*)(Kd + rowA * 128 + swA * 16)        = k0;
      *(short8*)(Kd + (rowA + 32) * 128 + swA * 16) = k1;
      *(short8*)(Vd + rowA * 128 + swA * 16)        = v0;
      *(short8*)(Vd + (rowA + 32) * 128 + swA * 16) = v1;
    };
    auto compute = [&](const char* Ks, const char* Vs, bool diag){
      f32x4 s4[4] = {};
      __builtin_amdgcn_s_setprio(1);
      #pragma unroll
      for (int j = 0; j < 4; j++){
        const int srow = j * 16 + l15, rm = srow & 7;
        const char* base = Ks + srow * 128;
        short8 b0 = *(const short8*)(base + ((l4 ^ rm) << 4));
        short8 b1 = *(const short8*)(base + (((4 + l4) ^ rm) << 4));
        mfma16(s4[j], qf0, b0);
        mfma16(s4[j], qf1, b1);
      }
      __builtin_amdgcn_s_setprio(0);
      float ps[4][4], lm[4];
      #pragma unroll
      for (int r = 0; r < 4; r++){
        float v0 = s4[0][r], v1 = s4[1][r], v2 = s4[2][r], v3 = s4[3][r];
        if (diag){
          int qrow = w * 16 + l4 * 4 + r;
          if (l15 > qrow)      v0 = -1e30f;
          if (16 + l15 > qrow) v1 = -1e30f;
          if (32 + l15 > qrow) v2 = -1e30f;
          if (48 + l15 > qrow) v3 = -1e30f;
        }
        lm[r] = fmaxf(fmaxf(v0, v1), fmaxf(v2, v3));   // per-lane max only
        ps[r][0] = v0; ps[r][1] = v1; ps[r][2] = v2; ps[r][3] = v3;
      }
      int ok = (lm[0] <= mrun[0] + 11.5f) && (lm[1] <= mrun[1] + 11.5f)
            && (lm[2] <= mrun[2] + 11.5f) && (lm[3] <= mrun[3] + 11.5f);
      if (!__all(ok)){
        #pragma unroll
        for (int r = 0; r < 4; r++){
          float mx = lm[r];
          mx = fmaxf(mx, __shfl_xor(mx, 1));
          mx = fmaxf(mx, __shfl_xor(mx, 2));
          mx = fmaxf(mx, __shfl_xor(mx, 4));
          mx = fmaxf(mx, __shfl_xor(mx, 8));
          float mnew = fmaxf(mrun[r], mx);
          float sc = EXP2(mrun[r] - mnew);
          mrun[r] = mnew;
          lsum[r] *= sc;
          o[0][r] *= sc; o[1][r] *= sc; o[2][r] *= sc; o[3][r] *= sc;
        }
      }
      #pragma unroll
      for (int r = 0; r < 4; r++){
        float p0 = EXP2(ps[r][0] - mrun[r]);
        float p1 = EXP2(ps[r][1] - mrun[r]);
        float p2 = EXP2(ps[r][2] - mrun[r]);
        float p3 = EXP2(ps[r][3] - mrun[r]);
        lsum[r] += (p0 + p1) + (p2 + p3);
        ps[r][0] = p0; ps[r][1] = p1; ps[r][2] = p2; ps[r][3] = p3;
      }
      char* pw = (char*)Psw;
      const int cb = (l15 & 7) * 2;
      #pragma unroll
      for (int r = 0; r < 4; r++){
        const int prow = l4 * 4 + r, rm = prow & 7;
        char* prb = pw + prow * 128 + cb;
        #pragma unroll
        for (int j = 0; j < 4; j++){
          int cj = (j * 2 + (l15 >> 3)) ^ rm;
          *((u16*)(prb + cj * 16)) = f2bf_rhu(ps[r][j]);
        }
      }
      const int prm = l15 & 7;
      short8 pa0 = *(const short8*)(pw + l15 * 128 + ((l4 ^ prm) << 4));
      short8 pa1 = *(const short8*)(pw + l15 * 128 + (((4 + l4) ^ prm) << 4));
      __builtin_amdgcn_s_setprio(1);
      #pragma unroll
      for (int j = 0; j < 4; j++){
        const int drow = j * 16 + l15, rm = drow & 7;
        const char* vb = Vs + drow * 128;
        short8 b0 = *(const short8*)(vb + ((l4 ^ rm) << 4));
        short8 b1 = *(const short8*)(vb + (((4 + l4) ^ rm) << 4));
        mfma16(o[j], pa0, b0);
        mfma16(o[j], pa1, b1);
      }
      __builtin_amdgcn_s_setprio(0);
    };

    // prologue: tile j lives in reg set (j&1)
    short8 kA0, kA1, vA0, vA1, kB0, kB1, vB0, vB1;
    stage_regs(0, kA0, kA1, vA0, vA1);
    lds_write(KsB, VsB, kA0, kA1, vA0, vA1);
    if (nkv > 1) stage_regs(1, kB0, kB1, vB0, vB1);
    if (nkv > 2) stage_regs(2, kA0, kA1, vA0, vA1);   // set A free after t0 write
    for (int i = 0; i < nkv; i += 2){
      __syncthreads();   // buf[i&1=0] writes visible; prior readers of buf1 done
      if (i + 1 < nkv){
        lds_write(KsB + 8192, VsB + 8192, kB0, kB1, vB0, vB1);   // tile i+1 -> buf1
        if (i + 3 < nkv) stage_regs(i + 3, kB0, kB1, vB0, vB1);  // 2-deep reissue
      }
      compute(KsB, VsB, i == qblk);
      if (i + 1 >= nkv) break;
      __syncthreads();   // buf1 writes visible; readers of buf0 done
      if (i + 2 < nkv){
        lds_write(KsB, VsB, kA0, kA1, vA0, vA1);                 // tile i+2 -> buf0
        if (i + 4 < nkv) stage_regs(i + 4, kA0, kA1, vA0, vA1);
      }
      compute(KsB + 8192, VsB + 8192, i + 1 == qblk);
    }
    #pragma unroll
    for (int r = 0; r < 4; r++){
      float ls = lsum[r];
      ls += __shfl_xor(ls, 1);
      ls += __shfl_xor(ls, 2);
      ls += __shfl_xor(ls, 4);
      ls += __shfl_xor(ls, 8);
      float inv = 1.f / ls;
      size_t base = (size_t)(bb * 2048 + q0 + l4 * 4 + r) * 1024 + h * 64;
      seqb[base + l15]      = f2bf(o[0][r] * inv);
      seqb[base + 16 + l15] = f2bf(o[1][r] * inv);
      seqb[base + 32 + l15] = f2bf(o[2][r] * inv);
      seqb[base + 48 + l15] = f2bf(o[3][r] * inv);
    }
  } else {
    float* Gl  = (float*)smem;               // [64][36]
    float* Jl  = (float*)(smem + 9216);      // [320][6]
    float* Bl  = (float*)(smem + 16896);     // [4][36]
    float* A64s= (float*)(smem + 17472);     // [36]
    float* Bw  = (float*)(smem + 17664);     // [36]
    float* Nw  = (float*)(smem + 17856);     // [36]
    const int local = blk;
    const int tblk = local & 7, bh = local >> 3, h = bh & 15;
    const int t0 = tblk * 256;
    for (int i = tid; i < 64 * 36; i += 256) Gl[i] = Gk[(size_t)h * 65 * 36 + i];
    {
      int base = t0 * 6 - 384;
      for (int i = tid; i < 1920; i += 256){
        int s6 = base + i;
        Jl[i] = (s6 >= 0) ? Jw[(size_t)bh * (2048 * 6) + s6] : 0.f;
      }
    }
    // ---- inline boundary prefix: B_0 = 0; B_{c+1} = A64 B_c A64^T + S_c ----
    {
      const int p = tid / 6, q = tid % 6;
      if (tid < 36){ A64s[tid] = Gk[((size_t)h * 65 + 64) * 36 + tid]; Bw[tid] = 0.f; }
      __syncthreads();
      float arow[6], acol[6];
      if (tid < 36){
        #pragma unroll
        for (int k = 0; k < 6; k++){ arow[k] = A64s[p * 6 + k]; acol[k] = A64s[q * 6 + k]; }
      }
      const int cEnd = tblk * 4;
      for (int c = 0; c < cEnd + 4; c++){
        if (tid < 36 && c >= cEnd) Bl[(c - cEnd) * 36 + tid] = Bw[tid];
        float n = 0.f;
        if (tid < 36){
          #pragma unroll
          for (int k = 0; k < 6; k++) n += arow[k] * Bw[k * 6 + q];
        }
        __syncthreads();
        if (tid < 36) Nw[tid] = n;
        __syncthreads();
        if (tid < 36){
          float m = Sb[((size_t)bh * 32 + c) * 36 + tid];
          #pragma unroll
          for (int k = 0; k < 6; k++) m += Nw[p * 6 + k] * acol[k];
          Bw[tid] = m;
        }
        __syncthreads();
      }
    }
    __syncthreads();
    float Ar[36];
    #pragma unroll
    for (int i = 0; i < 36; i++) Ar[i] = Gl[36 + i];   // A^1
    const int t = t0 + tid;
    const int cl = tid >> 6;
    const int dlt = tid & 63;
    float rdv[6];
    {
      const float* rp = rd + ((size_t)bh * 2048 + t) * 6;
      #pragma unroll
      for (int q = 0; q < 6; q++) rdv[q] = rp[q];
    }
    const float* g = Gl + dlt * 36;
    float u[6];
    #pragma unroll
    for (int p = 0; p < 6; p++){
      float s = 0.f;
      #pragma unroll
      for (int q = 0; q < 6; q++) s += rdv[q] * g[q * 6 + p];
      u[p] = s;
    }
    float acc = 0.f;
    #pragma unroll
    for (int p = 0; p < 6; p++){
      float bv = 0.f;
      #pragma unroll
      for (int q = 0; q < 6; q++) bv += Bl[cl * 36 + p * 6 + q] * u[q];
      acc += u[p] * bv;
    }
    float wv[6];
    #pragma unroll
    for (int q = 0; q < 6; q++) wv[q] = rdv[q];
    const int sIdx = tid + 63;
    for (int k = 0; k < dlt; k++){
      const float* jp = Jl + (sIdx - k) * 6;
      float uu = wv[0]*jp[0] + wv[1]*jp[1] + wv[2]*jp[2] + wv[3]*jp[3] + wv[4]*jp[4] + wv[5]*jp[5];
      acc += uu * uu;
      float nw[6];
      #pragma unroll
      for (int q = 0; q < 6; q++)
        nw[q] = wv[0]*Ar[q] + wv[1]*Ar[6+q] + wv[2]*Ar[12+q] + wv[3]*Ar[18+q] + wv[4]*Ar[24+q] + wv[5]*Ar[30+q];
      #pragma unroll
      for (int q = 0; q < 6; q++) wv[q] = nw[q];
    }
    score[(size_t)bh * 2048 + t] = acc;
  }
}

// ---------------- fused gated mean + combine ----------------
__global__ __launch_bounds__(256) void gated_combine_kernel(const float* __restrict__ score, const u16* __restrict__ C,
                                                            const float* __restrict__ mem_scale,
                                                            const u16* __restrict__ seqb, u16* __restrict__ preb)
{
  __shared__ float gsh[2];
  const int blk = blockIdx.x, tid = threadIdx.x;
  const int m0 = blk * 2;
  if (tid < 2){
    int m = m0 + tid;
    int b = m >> 11, t = m & 2047;
    float acc = 0.f;
    for (int h2 = 0; h2 < 16; h2++){
      float sc = score[(size_t)(b * 16 + h2) * 2048 + t];
      float ms = mem_scale[h2];
      float gp = bf2f(C[(size_t)m * LDC + 4352 + h2]);
      acc += sigm(sc * ms) * sigm(gp);
    }
    gsh[tid] = acc * (1.f / 16.f);
  }
  __syncthreads();
  const int m = m0 + (tid >> 7), d8 = (tid & 127) * 8;
  const float g = gsh[tid >> 7];
  short8 sv = *(const short8*)(seqb + (size_t)m * 1024 + d8);
  short8 mv = *(const short8*)(C + (size_t)m * LDC + 3328 + d8);
  short8 ov;
  #pragma unroll
  for (int j = 0; j < 8; j++){
    float f = bf2f((u16)sv[j]) + g * bf2f((u16)mv[j]);
    ov[j] = (short)f2bf(f);
  }
  *(short8*)(preb + (size_t)m * 1024 + d8) = ov;
}

// ---------------- launcher ----------------
extern "C" void kernel_launch(void* const* d_in, const int* in_sizes, int n_in,
                              void* d_out, int out_size, void* d_ws, size_t ws_size,
                              hipStream_t stream)
{
  (void)in_sizes; (void)n_in; (void)out_size; (void)ws_size;
  const float* x     = (const float*)d_in[0];
  const float* Wqkv  = (const float*)d_in[1];
  const float* bqkv  = (const float*)d_in[2];
  const float* W1w   = (const float*)d_in[3];
  const float* W2w   = (const float*)d_in[4];
  const float* W1r   = (const float*)d_in[5];
  const float* W2r   = (const float*)d_in[6];
  const float* Wmv   = (const float*)d_in[7];
  const float* bmv   = (const float*)d_in[8];
  const float* Wg    = (const float*)d_in[9];
  const float* bg    = (const float*)d_in[10];
  const float* mem_scale = (const float*)d_in[11];
  const float* Wout  = (const float*)d_in[12];
  const float* bout  = (const float*)d_in[13];
  const float* Am    = (const float*)d_in[14];
  float* out = (float*)d_out;

  char* p = (char*)d_ws;
  auto carve = [&](size_t bytes) -> void* {
    void* r = (void*)p;
    p += (bytes + 255) & ~(size_t)255;
    return r;
  };
  u16*   xb       = (u16*)  carve((size_t)4096 * 1024 * 2);
  u16*   C        = (u16*)  carve((size_t)4096 * LDC * 2);
  u16*   BT       = (u16*)  carve((size_t)LDC * 1024 * 2);
  u16*   WoutT    = (u16*)  carve((size_t)1024 * 1024 * 2);
  float* biasfull = (float*)carve((size_t)LDC * 4);
  u16*   VTb      = (u16*)  carve((size_t)32 * 64 * 2048 * 2);
  u16*   seqb     = (u16*)  carve((size_t)4096 * 1024 * 2);
  float* rdb      = (float*)carve((size_t)32 * 2048 * 6 * 4);
  float* Jwb      = (float*)carve((size_t)32 * 2048 * 6 * 4);
  float* Gk       = (float*)carve((size_t)16 * 65 * 36 * 4);
  float* Sbb      = (float*)carve((size_t)32 * 32 * 36 * 4);
  float* scoreb   = (float*)carve((size_t)32 * 2048 * 4);
  u16*   preb     = (u16*)  carve((size_t)4096 * 1024 * 2);

  prep_kernel<<<7474, 256, 0, stream>>>(x, bqkv, bmv, bg, Wqkv, W1w, W2w, W1r, W2r,
                                        Wmv, Wout, Wg, xb, biasfull, BT, WoutT);

  // fused projection GEMM (grid 1120 = 32 x 35)
  gemm_bt<u16><<<1120, 256, 0, stream>>>(xb, BT, biasfull, C, 4096, LDC, 1024, LDC);

  // chunk(+inline lines) | powers | transpose_v
  chunk_tv_kernel<<<4368, 256, 0, stream>>>(C, Am, Sbb, VTb, rdb, Jwb, Gk);

  // score (first, overlaps attn) + attention (2-deep reg prefetch)
  attn_score_kernel<<<1280, 256, 0, stream>>>(C, VTb, seqb, rdb, Jwb, Gk, Sbb, scoreb);

  gated_combine_kernel<<<2048, 256, 0, stream>>>(scoreb, C, mem_scale, seqb, preb);

  // final GEMM: out = pre @ Wout + bout (f32 out, grid 256 = 32 x 8)
  gemm_bt<float><<<256, 256, 0, stream>>>(preb, WoutT, bout, out, 4096, 1024, 1024, 1024);
}

// Round 17
// 168.315 us; speedup vs baseline: 1.0249x; 1.0249x over previous
//
#include <hip/hip_runtime.h>
#include <cstdint>
#include <cstddef>

typedef unsigned short u16;
typedef unsigned int u32;
typedef __attribute__((ext_vector_type(4))) float f32x4;
typedef __attribute__((ext_vector_type(4))) float float4v;
typedef __attribute__((ext_vector_type(8))) short short8;

#define LDC 4368   // fused GEMM output row stride (cols: qkv 0..3071 | w1 3072 | w2 3136 | r1 3200 | r2 3264 | mem_val 3328..4351 | gate 4352..4367)

__device__ __forceinline__ float bf2f(u16 u){ return __uint_as_float(((u32)u) << 16); }
__device__ __forceinline__ u16 f2bf(float f){
  u32 x = __float_as_uint(f);
  x += 0x7FFFu + ((x >> 16) & 1u);   // RNE
  return (u16)(x >> 16);
}
__device__ __forceinline__ u16 f2bf_rhu(float f){          // round-half-up (cheap, for P>=0)
  return (u16)((__float_as_uint(f) + 0x8000u) >> 16);
}
#if __has_builtin(__builtin_amdgcn_exp2f)
#define EXP2(x) __builtin_amdgcn_exp2f(x)
#else
#define EXP2(x) exp2f(x)
#endif
__device__ __forceinline__ void mfma16(f32x4& d, short8 a, short8 b){
  d = __builtin_amdgcn_mfma_f32_16x16x32_bf16(a, b, d, 0, 0, 0);
}
__device__ __forceinline__ void async_lds16(void* lds, const void* g){
  __builtin_amdgcn_global_load_lds((const __attribute__((address_space(1))) u32*)g,
                                   (__attribute__((address_space(3))) u32*)lds, 16, 0, 0);
}
__device__ __forceinline__ float sigm(float x){ return 1.f / (1.f + __expf(-x)); }
__device__ __forceinline__ void storev(u16* p, float v){ *p = f2bf(v); }
__device__ __forceinline__ void storev(float* p, float v){ *p = v; }

// ---------------- shared 32x32 convert+transpose helper ----------------
__device__ __forceinline__ void t32(const float* __restrict__ src, u16* __restrict__ dst,
                                    int R, int Ccols, int c0, int r0, int tid, u16 tile[32][33])
{
  int tx = tid & 31, ty0 = tid >> 5;
  #pragma unroll
  for (int i = 0; i < 4; i++){
    int r = r0 + ty0 + i * 8, c = c0 + tx;
    u16 v = 0;
    if (r < R && c < Ccols) v = f2bf(src[(size_t)r * Ccols + c]);
    tile[ty0 + i * 8][tx] = v;
  }
  __syncthreads();
  #pragma unroll
  for (int i = 0; i < 4; i++){
    int cc = c0 + ty0 + i * 8, rr = r0 + tx;
    if (cc < Ccols && rr < R) dst[(size_t)cc * R + rr] = tile[tx][ty0 + i * 8];
  }
}

// ---------------- fused preprocessing: cvt x | bias | all weight transposes ----------------
__global__ __launch_bounds__(256) void prep_kernel(
    const float* __restrict__ x, const float* __restrict__ bqkv, const float* __restrict__ bmv,
    const float* __restrict__ bg, const float* __restrict__ Wqkv,
    const float* __restrict__ W1w, const float* __restrict__ W2w,
    const float* __restrict__ W1r, const float* __restrict__ W2r,
    const float* __restrict__ Wmv, const float* __restrict__ Wout, const float* __restrict__ Wg,
    u16* __restrict__ xb, float* __restrict__ biasfull, u16* __restrict__ BT, u16* __restrict__ WoutT)
{
  __shared__ u16 tile[32][33];
  const int b = blockIdx.x, tid = threadIdx.x;
  if (b < 2048){
    int i = b * 256 + tid;   // 524288 total, exact
    float4v a = *(const float4v*)(x + (size_t)i * 8);
    float4v c = *(const float4v*)(x + (size_t)i * 8 + 4);
    short8 o;
    #pragma unroll
    for (int j = 0; j < 4; j++){ o[j] = (short)f2bf(a[j]); o[4 + j] = (short)f2bf(c[j]); }
    *(short8*)(xb + (size_t)i * 8) = o;
  } else if (b < 2066){
    int i = (b - 2048) * 256 + tid;
    if (i < 4368){
      float v;
      if (i < 3072) v = bqkv[i];
      else if (i < 3328) v = 0.f;
      else if (i < 4352) v = bmv[i - 3328];
      else v = bg[i - 4352];
      biasfull[i] = v;
    }
  } else if (b < 5138){
    int local = b - 2066;
    t32(Wqkv, BT, 1024, 3072, (local % 96) * 32, (local / 96) * 32, tid, tile);
  } else if (b < 5394){
    int local = b - 5138;
    int z = local >> 6, rem = local & 63;
    const float* src = (z == 0) ? W1w : (z == 1) ? W2w : (z == 2) ? W1r : W2r;
    t32(src, BT + (size_t)(3072 + z * 64) * 1024, 1024, 64, (rem & 1) * 32, (rem >> 1) * 32, tid, tile);
  } else if (b < 7442){
    int local = b - 5394;
    int z = local >> 10, rem = local & 1023;
    const float* src = z ? Wout : Wmv;
    u16* dst = z ? WoutT : (BT + (size_t)3328 * 1024);
    t32(src, dst, 1024, 1024, (rem & 31) * 32, (rem >> 5) * 32, tid, tile);
  } else {
    int local = b - 7442;
    t32(Wg, BT + (size_t)4352 * 1024, 1024, 16, 0, local * 32, tid, tile);
  }
}

// ---------------- MFMA GEMM: C(MxN) = A(MxK) * BT(NxK)^T + bias ----------------
// 128x128 tile, BK=32, 4 waves (2x2). Double-buffered LDS (32 KiB total).
// One barrier per K-step; next tile's global_load_lds issued BEFORE compute.
// LDS packs 2 global rows per 128B line; slot = ((r&1)*4 + kchunk) ^ (lrow&7):
// linear DMA dest + inverse-swizzled GLOBAL source + swizzled read (rule #21).
// 1D grid, bijective XCD swizzle (gridDim.x % 8 == 0).
template<typename OT>
__global__ __launch_bounds__(256) void gemm_bt(const u16* __restrict__ Ag, const u16* __restrict__ BTg,
                                               const float* __restrict__ bias, OT* __restrict__ Cg,
                                               int M, int N, int K, int ldc)
{
  __shared__ __align__(16) u16 As[2][128 * 32];   // 8 KiB per buffer
  __shared__ __align__(16) u16 Bs[2][128 * 32];
  const int tid = threadIdx.x, lane = tid & 63, w = tid >> 6;
  const int l15 = lane & 15, l4 = lane >> 4;
  const int qx = gridDim.x >> 3, bid = blockIdx.x;
  const int fid = (bid & 7) * qx + (bid >> 3);
  const int m0 = (fid & 31) * 128, n0 = (fid >> 5) * 128;
  const int wr = w >> 1, wc = w & 1;
  f32x4 acc[4][4] = {};
  const u16* aP[2]; const u16* bP[2];
  #pragma unroll
  for (int j = 0; j < 2; j++){
    int i = w * 128 + j * 64 + lane;
    int lrow = i >> 3, cc = i & 7;
    int sc = cc ^ (lrow & 7);
    int grow = lrow * 2 + (sc >> 2);
    int ka = (sc & 3) * 8;
    aP[j] = Ag + (size_t)(m0 + grow) * K + ka;
    int rb = n0 + grow; if (rb > N - 1) rb = N - 1;
    bP[j] = BTg + (size_t)rb * K + ka;
  }
  const int nk = K >> 5;
  #pragma unroll
  for (int j = 0; j < 2; j++){
    async_lds16((char*)As[0] + w * 2048 + j * 1024, aP[j]);
    async_lds16((char*)Bs[0] + w * 2048 + j * 1024, bP[j]);
  }
  __syncthreads();
  for (int t = 0; t < nk; t++){
    const int cur = t & 1;
    if (t + 1 < nk){
      const int k0 = (t + 1) << 5;
      char* An = (char*)As[cur ^ 1] + w * 2048;
      char* Bn = (char*)Bs[cur ^ 1] + w * 2048;
      #pragma unroll
      for (int j = 0; j < 2; j++){
        async_lds16(An + j * 1024, aP[j] + k0);
        async_lds16(Bn + j * 1024, bP[j] + k0);
      }
    }
    const char* Ab = (const char*)As[cur];
    const char* Bb = (const char*)Bs[cur];
    short8 a[4], b[4];
    #pragma unroll
    for (int mi = 0; mi < 4; mi++){
      int r = wr * 64 + mi * 16 + l15;
      int lrow = r >> 1;
      int slot = (((r & 1) << 2) + l4) ^ (lrow & 7);
      a[mi] = *(const short8*)(Ab + lrow * 128 + slot * 16);
    }
    #pragma unroll
    for (int ni = 0; ni < 4; ni++){
      int r = wc * 64 + ni * 16 + l15;
      int lrow = r >> 1;
      int slot = (((r & 1) << 2) + l4) ^ (lrow & 7);
      b[ni] = *(const short8*)(Bb + lrow * 128 + slot * 16);
    }
    #pragma unroll
    for (int mi = 0; mi < 4; mi++)
      #pragma unroll
      for (int ni = 0; ni < 4; ni++)
        mfma16(acc[mi][ni], a[mi], b[ni]);
    __syncthreads();
  }
  #pragma unroll
  for (int mi = 0; mi < 4; mi++){
    #pragma unroll
    for (int ni = 0; ni < 4; ni++){
      int col = n0 + wc * 64 + ni * 16 + l15;
      if (col < N){
        float bv = bias ? bias[col] : 0.f;
        #pragma unroll
        for (int r = 0; r < 4; r++){
          int row = m0 + wr * 64 + mi * 16 + l4 * 4 + r;
          storev(&Cg[(size_t)row * ldc + col], acc[mi][ni][r] + bv);
        }
      }
    }
  }
}

// ---------------- Plucker lines ----------------
__device__ __forceinline__ void ext6(float* L, const float* p, const float* q){
  L[0] = p[0]*q[1] - p[1]*q[0];
  L[1] = p[0]*q[2] - p[2]*q[0];
  L[2] = p[0]*q[3] - p[3]*q[0];
  L[3] = p[1]*q[2] - p[2]*q[1];
  L[4] = p[1]*q[3] - p[3]*q[1];
  L[5] = p[2]*q[3] - p[3]*q[2];
  float n = sqrtf(L[0]*L[0]+L[1]*L[1]+L[2]*L[2]+L[3]*L[3]+L[4]*L[4]+L[5]*L[5]);
  float inv = 1.f / fmaxf(n, 1e-12f);
  #pragma unroll
  for (int i = 0; i < 6; i++) L[i] *= inv;
}

// ---------------- fused: chunk+inline-lines [0,256) | powers [256,272) | transpose_v [272,4368) ----------------
__global__ __launch_bounds__(256) void chunk_tv_kernel(const u16* __restrict__ C, const float* __restrict__ Ain,
                                                       float* __restrict__ Sb, u16* __restrict__ VT,
                                                       float* __restrict__ rd, float* __restrict__ Jw,
                                                       float* __restrict__ Gk)
{
  __shared__ float Jl[4][384];
  __shared__ float Af[4][36], Ml[4][36], Nl[4][36];
  __shared__ u16 tile[32][33];
  __shared__ float Pw[36], Cur[36];
  const int blk = blockIdx.x, tid = threadIdx.x;
  if (blk < 256){
    const int g = tid >> 6, lt = tid & 63;
    const int task = blk * 4 + g;           // bh*32 + c
    const int c = task & 31, bh = task >> 5, h = bh & 15, b = bh >> 4;
    // ---- inline lines for t = c*64 + lt ----
    {
      const int t = c * 64 + lt;
      size_t m = (size_t)b * 2048 + t;
      float w1[4] = {0.f, 0.f, 0.f, 0.f}, w2[4], r1[4], r2[4];
      if (t > 0){
        const u16* p2 = C + (m - 1) * LDC + 3072 + h * 4;
        #pragma unroll
        for (int i = 0; i < 4; i++) w1[i] = bf2f(p2[i]);
      }
      {
        const u16* p2 = C + m * LDC + 3136 + h * 4;
        #pragma unroll
        for (int i = 0; i < 4; i++) w2[i] = bf2f(p2[i]);
        p2 = C + m * LDC + 3200 + h * 4;
        #pragma unroll
        for (int i = 0; i < 4; i++) r1[i] = bf2f(p2[i]);
        p2 = C + m * LDC + 3264 + h * 4;
        #pragma unroll
        for (int i = 0; i < 4; i++) r2[i] = bf2f(p2[i]);
      }
      float L[6], R[6];
      ext6(L, w1, w2);
      ext6(R, r1, r2);
      size_t o = ((size_t)bh * 2048 + t) * 6;
      #pragma unroll
      for (int i = 0; i < 6; i++) rd[o + i] = R[i];
      float jv[6] = { L[5], -L[4], L[3], L[2], -L[1], L[0] };   // write_lines @ J6
      #pragma unroll
      for (int i = 0; i < 6; i++){ Jw[o + i] = jv[i]; Jl[g][lt * 6 + i] = jv[i]; }
    }
    const int p = lt / 6, q = lt % 6;
    if (lt < 36){ Af[g][lt] = Ain[h * 36 + lt]; Ml[g][lt] = 0.f; }
    __syncthreads();
    float arow[6], acol[6];
    if (lt < 36){
      #pragma unroll
      for (int k = 0; k < 6; k++){ arow[k] = Af[g][p * 6 + k]; acol[k] = Af[g][q * 6 + k]; }
    }
    for (int s = 0; s < 64; s++){
      float n = 0.f;
      if (lt < 36){
        #pragma unroll
        for (int k = 0; k < 6; k++) n += arow[k] * Ml[g][k * 6 + q];
        Nl[g][lt] = n;
      }
      __syncthreads();
      if (lt < 36){
        float m = Jl[g][s * 6 + p] * Jl[g][s * 6 + q];
        #pragma unroll
        for (int k = 0; k < 6; k++) m += Nl[g][p * 6 + k] * acol[k];
        Ml[g][lt] = m;
      }
      __syncthreads();
    }
    if (lt < 36) Sb[((size_t)bh * 32 + c) * 36 + lt] = Ml[g][lt];
  } else if (blk < 272){
    // ---- powers: Gk[h][k] = A^k, k = 0..64 ----
    const int h = blk - 256;
    const int p = tid / 6, q = tid % 6;
    if (tid < 36){
      Pw[tid] = Ain[h * 36 + tid];
      float id = (p == q) ? 1.f : 0.f;
      Cur[tid] = id;
      Gk[(size_t)h * 65 * 36 + tid] = id;
    }
    __syncthreads();
    for (int k = 1; k <= 64; k++){
      float v = 0.f;
      if (tid < 36){
        #pragma unroll
        for (int j = 0; j < 6; j++) v += Cur[p * 6 + j] * Pw[j * 6 + q];
      }
      __syncthreads();
      if (tid < 36){
        Cur[tid] = v;
        Gk[((size_t)h * 65 + k) * 36 + tid] = v;
      }
      __syncthreads();
    }
  } else {
    // ---- transpose_v ----
    int local = blk - 272;
    int bh = local >> 7, rem = local & 127;
    int b = bh >> 4, h = bh & 15;
    const u16* src = C + (size_t)b * 2048 * LDC + 2048 + h * 64;
    int c0 = (rem & 1) * 32, r0 = (rem >> 1) * 32;
    int tx = tid & 31, ty0 = tid >> 5;
    #pragma unroll
    for (int i = 0; i < 4; i++)
      tile[ty0 + i * 8][tx] = src[(size_t)(r0 + ty0 + i * 8) * LDC + c0 + tx];
    __syncthreads();
    u16* dstb = VT + (size_t)bh * 64 * 2048;
    #pragma unroll
    for (int i = 0; i < 4; i++)
      dstb[(size_t)(c0 + ty0 + i * 8) * 2048 + r0 + tx] = tile[tx][ty0 + i * 8];
  }
}

// ---------------- fused score [0,256) + attention [256,1280) ----------------
// Score blocks dispatch FIRST (overlap attn's shadow). attn: K/V LDS
// double-buffered, one barrier per KV-iter, single-deep register prefetch
// (R15 version; R16's 2-deep variant regressed). Q pre-scaled by
// 0.125*log2(e); per-lane l-sums; defer-max THR=11.5 fast path; T5 setprio.
// score: computes its own boundary prefix B_c from Sb+Gk (<=32 serial steps).
__global__ __launch_bounds__(256) void attn_score_kernel(const u16* __restrict__ C, const u16* __restrict__ VT,
                                                         u16* __restrict__ seqb,
                                                         const float* __restrict__ rd, const float* __restrict__ Jw,
                                                         const float* __restrict__ Gk, const float* __restrict__ Sb,
                                                         float* __restrict__ score)
{
  __shared__ __align__(16) char smem[40960];
  const int blk = blockIdx.x, tid = threadIdx.x;
  if (blk >= 256){
    char* KsB = smem;                        // [2][64][64] swizzled
    char* VsB = smem + 16384;                // [2][64][64]
    const int abk = blk - 256;
    const int bh = abk & 31, bb = bh >> 4, h = bh & 15;
    const int qblk = 31 - (abk >> 5);
    const int lane = tid & 63, w = tid >> 6;
    const int l15 = lane & 15, l4 = lane >> 4;
    u16* Psw = (u16*)(smem + 32768) + w * 1024;   // per-wave [16][64]
    const int q0 = qblk * 64 + w * 16;
    const float csc = 0.1803368801f;   // 0.125 * log2(e)
    const u16* qb = C + (size_t)(bb * 2048 + q0 + l15) * LDC + h * 64 + l4 * 8;
    short8 qf0 = *(const short8*)qb;
    short8 qf1 = *(const short8*)(qb + 32);
    #pragma unroll
    for (int j = 0; j < 8; j++){
      qf0[j] = (short)f2bf(bf2f((u16)qf0[j]) * csc);
      qf1[j] = (short)f2bf(bf2f((u16)qf1[j]) * csc);
    }
    f32x4 o[4] = {};
    float mrun[4], lsum[4];
    #pragma unroll
    for (int r = 0; r < 4; r++){ mrun[r] = -1e30f; lsum[r] = 0.f; }
    const int nkv = qblk + 1;
    const int rowA = tid >> 3, chA = tid & 7;
    const int swA = chA ^ (rowA & 7);
    const u16* Kg = C + (size_t)(bb * 2048) * LDC + 1024 + h * 64 + chA * 8;
    const u16* Vg = VT + ((size_t)bh * 64 + rowA) * 2048 + chA * 8;
    short8 kr0, kr1, vr0, vr1;
    // tile 0 -> regs -> buf0
    kr0 = *(const short8*)(Kg + (size_t)rowA * LDC);
    kr1 = *(const short8*)(Kg + (size_t)(rowA + 32) * LDC);
    vr0 = *(const short8*)(Vg);
    vr1 = *(const short8*)(Vg + 32 * 2048);
    *(short8*)(KsB + rowA * 128 + swA * 16)        = kr0;
    *(short8*)(KsB + (rowA + 32) * 128 + swA * 16) = kr1;
    *(short8*)(VsB + rowA * 128 + swA * 16)        = vr0;
    *(short8*)(VsB + (rowA + 32) * 128 + swA * 16) = vr1;
    if (nkv > 1){   // prefetch tile 1 into regs
      kr0 = *(const short8*)(Kg + (size_t)(64 + rowA) * LDC);
      kr1 = *(const short8*)(Kg + (size_t)(64 + rowA + 32) * LDC);
      vr0 = *(const short8*)(Vg + 64);
      vr1 = *(const short8*)(Vg + 64 + 32 * 2048);
    }
    for (int i = 0; i < nkv; i++){
      const int cur = i & 1;
      __syncthreads();   // buf[cur] writes visible; buf[cur^1] readers (iter i-1) done
      if (i + 1 < nkv){
        char* Kd = KsB + (cur ^ 1) * 8192;
        char* Vd = VsB + (cur ^ 1) * 8192;
        *(short8*)(Kd + rowA * 128 + swA * 16)        = kr0;
        *(short8*)(Kd + (rowA + 32) * 128 + swA * 16) = kr1;
        *(short8*)(Vd + rowA * 128 + swA * 16)        = vr0;
        *(short8*)(Vd + (rowA + 32) * 128 + swA * 16) = vr1;
        if (i + 2 < nkv){   // WAR on regs is safe: ds_write samples at issue
          int nx = (i + 2) * 64;
          kr0 = *(const short8*)(Kg + (size_t)(nx + rowA) * LDC);
          kr1 = *(const short8*)(Kg + (size_t)(nx + rowA + 32) * LDC);
          vr0 = *(const short8*)(Vg + nx);
          vr1 = *(const short8*)(Vg + nx + 32 * 2048);
        }
      }
      const char* Ks = KsB + cur * 8192;
      const char* Vs = VsB + cur * 8192;
      const bool diag = (i == qblk);
      f32x4 s4[4] = {};
      __builtin_amdgcn_s_setprio(1);
      #pragma unroll
      for (int j = 0; j < 4; j++){
        const int srow = j * 16 + l15, rm = srow & 7;
        const char* base = Ks + srow * 128;
        short8 b0 = *(const short8*)(base + ((l4 ^ rm) << 4));
        short8 b1 = *(const short8*)(base + (((4 + l4) ^ rm) << 4));
        mfma16(s4[j], qf0, b0);
        mfma16(s4[j], qf1, b1);
      }
      __builtin_amdgcn_s_setprio(0);
      float ps[4][4], lm[4];
      #pragma unroll
      for (int r = 0; r < 4; r++){
        float v0 = s4[0][r], v1 = s4[1][r], v2 = s4[2][r], v3 = s4[3][r];
        if (diag){
          int qrow = w * 16 + l4 * 4 + r;
          if (l15 > qrow)      v0 = -1e30f;
          if (16 + l15 > qrow) v1 = -1e30f;
          if (32 + l15 > qrow) v2 = -1e30f;
          if (48 + l15 > qrow) v3 = -1e30f;
        }
        lm[r] = fmaxf(fmaxf(v0, v1), fmaxf(v2, v3));   // per-lane max only
        ps[r][0] = v0; ps[r][1] = v1; ps[r][2] = v2; ps[r][3] = v3;
      }
      int ok = (lm[0] <= mrun[0] + 11.5f) && (lm[1] <= mrun[1] + 11.5f)
            && (lm[2] <= mrun[2] + 11.5f) && (lm[3] <= mrun[3] + 11.5f);
      if (!__all(ok)){
        #pragma unroll
        for (int r = 0; r < 4; r++){
          float mx = lm[r];
          mx = fmaxf(mx, __shfl_xor(mx, 1));
          mx = fmaxf(mx, __shfl_xor(mx, 2));
          mx = fmaxf(mx, __shfl_xor(mx, 4));
          mx = fmaxf(mx, __shfl_xor(mx, 8));
          float mnew = fmaxf(mrun[r], mx);
          float sc = EXP2(mrun[r] - mnew);
          mrun[r] = mnew;
          lsum[r] *= sc;
          o[0][r] *= sc; o[1][r] *= sc; o[2][r] *= sc; o[3][r] *= sc;
        }
      }
      #pragma unroll
      for (int r = 0; r < 4; r++){
        float p0 = EXP2(ps[r][0] - mrun[r]);
        float p1 = EXP2(ps[r][1] - mrun[r]);
        float p2 = EXP2(ps[r][2] - mrun[r]);
        float p3 = EXP2(ps[r][3] - mrun[r]);
        lsum[r] += (p0 + p1) + (p2 + p3);
        ps[r][0] = p0; ps[r][1] = p1; ps[r][2] = p2; ps[r][3] = p3;
      }
      char* pw = (char*)Psw;
      const int cb = (l15 & 7) * 2;
      #pragma unroll
      for (int r = 0; r < 4; r++){
        const int prow = l4 * 4 + r, rm = prow & 7;
        char* prb = pw + prow * 128 + cb;
        #pragma unroll
        for (int j = 0; j < 4; j++){
          int cj = (j * 2 + (l15 >> 3)) ^ rm;
          *((u16*)(prb + cj * 16)) = f2bf_rhu(ps[r][j]);
        }
      }
      const int prm = l15 & 7;
      short8 pa0 = *(const short8*)(pw + l15 * 128 + ((l4 ^ prm) << 4));
      short8 pa1 = *(const short8*)(pw + l15 * 128 + (((4 + l4) ^ prm) << 4));
      __builtin_amdgcn_s_setprio(1);
      #pragma unroll
      for (int j = 0; j < 4; j++){
        const int drow = j * 16 + l15, rm = drow & 7;
        const char* vb = Vs + drow * 128;
        short8 b0 = *(const short8*)(vb + ((l4 ^ rm) << 4));
        short8 b1 = *(const short8*)(vb + (((4 + l4) ^ rm) << 4));
        mfma16(o[j], pa0, b0);
        mfma16(o[j], pa1, b1);
      }
      __builtin_amdgcn_s_setprio(0);
    }
    #pragma unroll
    for (int r = 0; r < 4; r++){
      float ls = lsum[r];
      ls += __shfl_xor(ls, 1);
      ls += __shfl_xor(ls, 2);
      ls += __shfl_xor(ls, 4);
      ls += __shfl_xor(ls, 8);
      float inv = 1.f / ls;
      size_t base = (size_t)(bb * 2048 + q0 + l4 * 4 + r) * 1024 + h * 64;
      seqb[base + l15]      = f2bf(o[0][r] * inv);
      seqb[base + 16 + l15] = f2bf(o[1][r] * inv);
      seqb[base + 32 + l15] = f2bf(o[2][r] * inv);
      seqb[base + 48 + l15] = f2bf(o[3][r] * inv);
    }
  } else {
    float* Gl  = (float*)smem;               // [64][36]
    float* Jl  = (float*)(smem + 9216);      // [320][6]
    float* Bl  = (float*)(smem + 16896);     // [4][36]
    float* A64s= (float*)(smem + 17472);     // [36]
    float* Bw  = (float*)(smem + 17664);     // [36]
    float* Nw  = (float*)(smem + 17856);     // [36]
    const int local = blk;
    const int tblk = local & 7, bh = local >> 3, h = bh & 15;
    const int t0 = tblk * 256;
    for (int i = tid; i < 64 * 36; i += 256) Gl[i] = Gk[(size_t)h * 65 * 36 + i];
    {
      int base = t0 * 6 - 384;
      for (int i = tid; i < 1920; i += 256){
        int s6 = base + i;
        Jl[i] = (s6 >= 0) ? Jw[(size_t)bh * (2048 * 6) + s6] : 0.f;
      }
    }
    // ---- inline boundary prefix: B_0 = 0; B_{c+1} = A64 B_c A64^T + S_c ----
    {
      const int p = tid / 6, q = tid % 6;
      if (tid < 36){ A64s[tid] = Gk[((size_t)h * 65 + 64) * 36 + tid]; Bw[tid] = 0.f; }
      __syncthreads();
      float arow[6], acol[6];
      if (tid < 36){
        #pragma unroll
        for (int k = 0; k < 6; k++){ arow[k] = A64s[p * 6 + k]; acol[k] = A64s[q * 6 + k]; }
      }
      const int cEnd = tblk * 4;
      for (int c = 0; c < cEnd + 4; c++){
        if (tid < 36 && c >= cEnd) Bl[(c - cEnd) * 36 + tid] = Bw[tid];
        float n = 0.f;
        if (tid < 36){
          #pragma unroll
          for (int k = 0; k < 6; k++) n += arow[k] * Bw[k * 6 + q];
        }
        __syncthreads();
        if (tid < 36) Nw[tid] = n;
        __syncthreads();
        if (tid < 36){
          float m = Sb[((size_t)bh * 32 + c) * 36 + tid];
          #pragma unroll
          for (int k = 0; k < 6; k++) m += Nw[p * 6 + k] * acol[k];
          Bw[tid] = m;
        }
        __syncthreads();
      }
    }
    __syncthreads();
    float Ar[36];
    #pragma unroll
    for (int i = 0; i < 36; i++) Ar[i] = Gl[36 + i];   // A^1
    const int t = t0 + tid;
    const int cl = tid >> 6;
    const int dlt = tid & 63;
    float rdv[6];
    {
      const float* rp = rd + ((size_t)bh * 2048 + t) * 6;
      #pragma unroll
      for (int q = 0; q < 6; q++) rdv[q] = rp[q];
    }
    const float* g = Gl + dlt * 36;
    float u[6];
    #pragma unroll
    for (int p = 0; p < 6; p++){
      float s = 0.f;
      #pragma unroll
      for (int q = 0; q < 6; q++) s += rdv[q] * g[q * 6 + p];
      u[p] = s;
    }
    float acc = 0.f;
    #pragma unroll
    for (int p = 0; p < 6; p++){
      float bv = 0.f;
      #pragma unroll
      for (int q = 0; q < 6; q++) bv += Bl[cl * 36 + p * 6 + q] * u[q];
      acc += u[p] * bv;
    }
    float wv[6];
    #pragma unroll
    for (int q = 0; q < 6; q++) wv[q] = rdv[q];
    const int sIdx = tid + 63;
    for (int k = 0; k < dlt; k++){
      const float* jp = Jl + (sIdx - k) * 6;
      float uu = wv[0]*jp[0] + wv[1]*jp[1] + wv[2]*jp[2] + wv[3]*jp[3] + wv[4]*jp[4] + wv[5]*jp[5];
      acc += uu * uu;
      float nw[6];
      #pragma unroll
      for (int q = 0; q < 6; q++)
        nw[q] = wv[0]*Ar[q] + wv[1]*Ar[6+q] + wv[2]*Ar[12+q] + wv[3]*Ar[18+q] + wv[4]*Ar[24+q] + wv[5]*Ar[30+q];
      #pragma unroll
      for (int q = 0; q < 6; q++) wv[q] = nw[q];
    }
    score[(size_t)bh * 2048 + t] = acc;
  }
}

// ---------------- fused gated mean + combine ----------------
// 32 lanes (2 rows x 16 heads) compute the gate products in parallel,
// 16-lane shuffle reduce (was: 2 threads x 16 serial dependent loads).
__global__ __launch_bounds__(256) void gated_combine_kernel(const float* __restrict__ score, const u16* __restrict__ C,
                                                            const float* __restrict__ mem_scale,
                                                            const u16* __restrict__ seqb, u16* __restrict__ preb)
{
  __shared__ float gsh[2];
  const int blk = blockIdx.x, tid = threadIdx.x;
  const int m0 = blk * 2;
  if (tid < 32){
    const int mm = tid >> 4, h2 = tid & 15;
    const int m = m0 + mm;
    const int b = m >> 11, t = m & 2047;
    float sc = score[(size_t)(b * 16 + h2) * 2048 + t];
    float v = sigm(sc * mem_scale[h2]) * sigm(bf2f(C[(size_t)m * LDC + 4352 + h2]));
    v += __shfl_xor(v, 1);
    v += __shfl_xor(v, 2);
    v += __shfl_xor(v, 4);
    v += __shfl_xor(v, 8);
    if (h2 == 0) gsh[mm] = v * (1.f / 16.f);
  }
  __syncthreads();
  const int m = m0 + (tid >> 7), d8 = (tid & 127) * 8;
  const float g = gsh[tid >> 7];
  short8 sv = *(const short8*)(seqb + (size_t)m * 1024 + d8);
  short8 mv = *(const short8*)(C + (size_t)m * LDC + 3328 + d8);
  short8 ov;
  #pragma unroll
  for (int j = 0; j < 8; j++){
    float f = bf2f((u16)sv[j]) + g * bf2f((u16)mv[j]);
    ov[j] = (short)f2bf(f);
  }
  *(short8*)(preb + (size_t)m * 1024 + d8) = ov;
}

// ---------------- launcher ----------------
extern "C" void kernel_launch(void* const* d_in, const int* in_sizes, int n_in,
                              void* d_out, int out_size, void* d_ws, size_t ws_size,
                              hipStream_t stream)
{
  (void)in_sizes; (void)n_in; (void)out_size; (void)ws_size;
  const float* x     = (const float*)d_in[0];
  const float* Wqkv  = (const float*)d_in[1];
  const float* bqkv  = (const float*)d_in[2];
  const float* W1w   = (const float*)d_in[3];
  const float* W2w   = (const float*)d_in[4];
  const float* W1r   = (const float*)d_in[5];
  const float* W2r   = (const float*)d_in[6];
  const float* Wmv   = (const float*)d_in[7];
  const float* bmv   = (const float*)d_in[8];
  const float* Wg    = (const float*)d_in[9];
  const float* bg    = (const float*)d_in[10];
  const float* mem_scale = (const float*)d_in[11];
  const float* Wout  = (const float*)d_in[12];
  const float* bout  = (const float*)d_in[13];
  const float* Am    = (const float*)d_in[14];
  float* out = (float*)d_out;

  char* p = (char*)d_ws;
  auto carve = [&](size_t bytes) -> void* {
    void* r = (void*)p;
    p += (bytes + 255) & ~(size_t)255;
    return r;
  };
  u16*   xb       = (u16*)  carve((size_t)4096 * 1024 * 2);
  u16*   C        = (u16*)  carve((size_t)4096 * LDC * 2);
  u16*   BT       = (u16*)  carve((size_t)LDC * 1024 * 2);
  u16*   WoutT    = (u16*)  carve((size_t)1024 * 1024 * 2);
  float* biasfull = (float*)carve((size_t)LDC * 4);
  u16*   VTb      = (u16*)  carve((size_t)32 * 64 * 2048 * 2);
  u16*   seqb     = (u16*)  carve((size_t)4096 * 1024 * 2);
  float* rdb      = (float*)carve((size_t)32 * 2048 * 6 * 4);
  float* Jwb      = (float*)carve((size_t)32 * 2048 * 6 * 4);
  float* Gk       = (float*)carve((size_t)16 * 65 * 36 * 4);
  float* Sbb      = (float*)carve((size_t)32 * 32 * 36 * 4);
  float* scoreb   = (float*)carve((size_t)32 * 2048 * 4);
  u16*   preb     = (u16*)  carve((size_t)4096 * 1024 * 2);

  prep_kernel<<<7474, 256, 0, stream>>>(x, bqkv, bmv, bg, Wqkv, W1w, W2w, W1r, W2r,
                                        Wmv, Wout, Wg, xb, biasfull, BT, WoutT);

  // fused projection GEMM (grid 1120 = 32 x 35)
  gemm_bt<u16><<<1120, 256, 0, stream>>>(xb, BT, biasfull, C, 4096, LDC, 1024, LDC);

  // chunk(+inline lines) | powers | transpose_v
  chunk_tv_kernel<<<4368, 256, 0, stream>>>(C, Am, Sbb, VTb, rdb, Jwb, Gk);

  // score (first, overlaps attn) + attention
  attn_score_kernel<<<1280, 256, 0, stream>>>(C, VTb, seqb, rdb, Jwb, Gk, Sbb, scoreb);

  gated_combine_kernel<<<2048, 256, 0, stream>>>(scoreb, C, mem_scale, seqb, preb);

  // final GEMM: out = pre @ Wout + bout (f32 out, grid 256 = 32 x 8)
  gemm_bt<float><<<256, 256, 0, stream>>>(preb, WoutT, bout, out, 4096, 1024, 1024, 1024);
}

// Round 18
// 164.900 us; speedup vs baseline: 1.0462x; 1.0207x over previous
//
#include <hip/hip_runtime.h>
#include <cstdint>
#include <cstddef>

typedef unsigned short u16;
typedef unsigned int u32;
typedef __attribute__((ext_vector_type(4))) float f32x4;
typedef __attribute__((ext_vector_type(4))) float float4v;
typedef __attribute__((ext_vector_type(8))) short short8;

#define LDC 4368   // fused GEMM output row stride (cols: qkv 0..3071 | w1 3072 | w2 3136 | r1 3200 | r2 3264 | mem_val 3328..4351 | gate 4352..4367)

__device__ __forceinline__ float bf2f(u16 u){ return __uint_as_float(((u32)u) << 16); }
__device__ __forceinline__ u16 f2bf(float f){
  u32 x = __float_as_uint(f);
  x += 0x7FFFu + ((x >> 16) & 1u);   // RNE
  return (u16)(x >> 16);
}
__device__ __forceinline__ u16 f2bf_rhu(float f){          // round-half-up (cheap, for P>=0)
  return (u16)((__float_as_uint(f) + 0x8000u) >> 16);
}
#if __has_builtin(__builtin_amdgcn_exp2f)
#define EXP2(x) __builtin_amdgcn_exp2f(x)
#else
#define EXP2(x) exp2f(x)
#endif
__device__ __forceinline__ void mfma16(f32x4& d, short8 a, short8 b){
  d = __builtin_amdgcn_mfma_f32_16x16x32_bf16(a, b, d, 0, 0, 0);
}
__device__ __forceinline__ void async_lds16(void* lds, const void* g){
  __builtin_amdgcn_global_load_lds((const __attribute__((address_space(1))) u32*)g,
                                   (__attribute__((address_space(3))) u32*)lds, 16, 0, 0);
}
__device__ __forceinline__ float sigm(float x){ return 1.f / (1.f + __expf(-x)); }
__device__ __forceinline__ void storev(u16* p, float v){ *p = f2bf(v); }
__device__ __forceinline__ void storev(float* p, float v){ *p = v; }

// ---------------- shared 32x32 convert+transpose helper ----------------
__device__ __forceinline__ void t32(const float* __restrict__ src, u16* __restrict__ dst,
                                    int R, int Ccols, int c0, int r0, int tid, u16 tile[32][33])
{
  int tx = tid & 31, ty0 = tid >> 5;
  #pragma unroll
  for (int i = 0; i < 4; i++){
    int r = r0 + ty0 + i * 8, c = c0 + tx;
    u16 v = 0;
    if (r < R && c < Ccols) v = f2bf(src[(size_t)r * Ccols + c]);
    tile[ty0 + i * 8][tx] = v;
  }
  __syncthreads();
  #pragma unroll
  for (int i = 0; i < 4; i++){
    int cc = c0 + ty0 + i * 8, rr = r0 + tx;
    if (cc < Ccols && rr < R) dst[(size_t)cc * R + rr] = tile[tx][ty0 + i * 8];
  }
}

// ---------------- fused preprocessing: cvt x | bias | all weight transposes ----------------
__global__ __launch_bounds__(256) void prep_kernel(
    const float* __restrict__ x, const float* __restrict__ bqkv, const float* __restrict__ bmv,
    const float* __restrict__ bg, const float* __restrict__ Wqkv,
    const float* __restrict__ W1w, const float* __restrict__ W2w,
    const float* __restrict__ W1r, const float* __restrict__ W2r,
    const float* __restrict__ Wmv, const float* __restrict__ Wout, const float* __restrict__ Wg,
    u16* __restrict__ xb, float* __restrict__ biasfull, u16* __restrict__ BT, u16* __restrict__ WoutT)
{
  __shared__ u16 tile[32][33];
  const int b = blockIdx.x, tid = threadIdx.x;
  if (b < 2048){
    int i = b * 256 + tid;   // 524288 total, exact
    float4v a = *(const float4v*)(x + (size_t)i * 8);
    float4v c = *(const float4v*)(x + (size_t)i * 8 + 4);
    short8 o;
    #pragma unroll
    for (int j = 0; j < 4; j++){ o[j] = (short)f2bf(a[j]); o[4 + j] = (short)f2bf(c[j]); }
    *(short8*)(xb + (size_t)i * 8) = o;
  } else if (b < 2066){
    int i = (b - 2048) * 256 + tid;
    if (i < 4368){
      float v;
      if (i < 3072) v = bqkv[i];
      else if (i < 3328) v = 0.f;
      else if (i < 4352) v = bmv[i - 3328];
      else v = bg[i - 4352];
      biasfull[i] = v;
    }
  } else if (b < 5138){
    int local = b - 2066;
    t32(Wqkv, BT, 1024, 3072, (local % 96) * 32, (local / 96) * 32, tid, tile);
  } else if (b < 5394){
    int local = b - 5138;
    int z = local >> 6, rem = local & 63;
    const float* src = (z == 0) ? W1w : (z == 1) ? W2w : (z == 2) ? W1r : W2r;
    t32(src, BT + (size_t)(3072 + z * 64) * 1024, 1024, 64, (rem & 1) * 32, (rem >> 1) * 32, tid, tile);
  } else if (b < 7442){
    int local = b - 5394;
    int z = local >> 10, rem = local & 1023;
    const float* src = z ? Wout : Wmv;
    u16* dst = z ? WoutT : (BT + (size_t)3328 * 1024);
    t32(src, dst, 1024, 1024, (rem & 31) * 32, (rem >> 5) * 32, tid, tile);
  } else {
    int local = b - 7442;
    t32(Wg, BT + (size_t)4352 * 1024, 1024, 16, 0, local * 32, tid, tile);
  }
}

// ---------------- MFMA GEMM: C(MxN) = A(MxK) * BT(NxK)^T + bias ----------------
// 128xBN tile (BN=128 or 64), BK=32, 4 waves (2x2). Double-buffered LDS.
// One barrier per K-step; next tile's global_load_lds issued BEFORE compute.
// LDS packs 2 global rows per 128B line; slot = ((r&1)*4 + kchunk) ^ (lrow&7):
// linear DMA dest + inverse-swizzled GLOBAL source + swizzled read (rule #21).
// 1D grid (32 M-tiles x N/BN N-tiles), bijective XCD swizzle (grid % 8 == 0).
// BN=64 halves the tile for the small-N final GEMM -> grid 512 = 2 blocks/CU.
template<typename OT, int BN>
__global__ __launch_bounds__(256) void gemm_bt(const u16* __restrict__ Ag, const u16* __restrict__ BTg,
                                               const float* __restrict__ bias, OT* __restrict__ Cg,
                                               int M, int N, int K, int ldc)
{
  constexpr int BJ = BN / 64;        // B staging chunks per thread
  constexpr int NF = BN / 32;        // N-frags per wave (wave col width BN/2)
  __shared__ __align__(16) u16 As[2][128 * 32];   // 8 KiB per buffer
  __shared__ __align__(16) u16 Bs[2][BN * 32];
  const int tid = threadIdx.x, lane = tid & 63, w = tid >> 6;
  const int l15 = lane & 15, l4 = lane >> 4;
  const int qx = gridDim.x >> 3, bid = blockIdx.x;
  const int fid = (bid & 7) * qx + (bid >> 3);
  const int m0 = (fid & 31) * 128, n0 = (fid >> 5) * BN;
  const int wr = w >> 1, wc = w & 1;
  f32x4 acc[4][NF] = {};
  const u16* aP[2]; const u16* bP[BJ];
  #pragma unroll
  for (int j = 0; j < 2; j++){
    int i = w * 128 + j * 64 + lane;
    int lrow = i >> 3, cc = i & 7;
    int sc = cc ^ (lrow & 7);
    int grow = lrow * 2 + (sc >> 2);
    int ka = (sc & 3) * 8;
    aP[j] = Ag + (size_t)(m0 + grow) * K + ka;
  }
  #pragma unroll
  for (int j = 0; j < BJ; j++){
    int i = w * (64 * BJ) + j * 64 + lane;
    int lrow = i >> 3, cc = i & 7;
    int sc = cc ^ (lrow & 7);
    int grow = lrow * 2 + (sc >> 2);
    int ka = (sc & 3) * 8;
    int rb = n0 + grow; if (rb > N - 1) rb = N - 1;
    bP[j] = BTg + (size_t)rb * K + ka;
  }
  const int nk = K >> 5;
  #pragma unroll
  for (int j = 0; j < 2; j++)
    async_lds16((char*)As[0] + w * 2048 + j * 1024, aP[j]);
  #pragma unroll
  for (int j = 0; j < BJ; j++)
    async_lds16((char*)Bs[0] + w * (BJ * 1024) + j * 1024, bP[j]);
  __syncthreads();
  for (int t = 0; t < nk; t++){
    const int cur = t & 1;
    if (t + 1 < nk){
      const int k0 = (t + 1) << 5;
      char* An = (char*)As[cur ^ 1] + w * 2048;
      char* Bn = (char*)Bs[cur ^ 1] + w * (BJ * 1024);
      #pragma unroll
      for (int j = 0; j < 2; j++)
        async_lds16(An + j * 1024, aP[j] + k0);
      #pragma unroll
      for (int j = 0; j < BJ; j++)
        async_lds16(Bn + j * 1024, bP[j] + k0);
    }
    const char* Ab = (const char*)As[cur];
    const char* Bb = (const char*)Bs[cur];
    short8 a[4], b[NF];
    #pragma unroll
    for (int mi = 0; mi < 4; mi++){
      int r = wr * 64 + mi * 16 + l15;
      int lrow = r >> 1;
      int slot = (((r & 1) << 2) + l4) ^ (lrow & 7);
      a[mi] = *(const short8*)(Ab + lrow * 128 + slot * 16);
    }
    #pragma unroll
    for (int ni = 0; ni < NF; ni++){
      int r = wc * (BN / 2) + ni * 16 + l15;
      int lrow = r >> 1;
      int slot = (((r & 1) << 2) + l4) ^ (lrow & 7);
      b[ni] = *(const short8*)(Bb + lrow * 128 + slot * 16);
    }
    #pragma unroll
    for (int mi = 0; mi < 4; mi++)
      #pragma unroll
      for (int ni = 0; ni < NF; ni++)
        mfma16(acc[mi][ni], a[mi], b[ni]);
    __syncthreads();
  }
  #pragma unroll
  for (int mi = 0; mi < 4; mi++){
    #pragma unroll
    for (int ni = 0; ni < NF; ni++){
      int col = n0 + wc * (BN / 2) + ni * 16 + l15;
      if (col < N){
        float bv = bias ? bias[col] : 0.f;
        #pragma unroll
        for (int r = 0; r < 4; r++){
          int row = m0 + wr * 64 + mi * 16 + l4 * 4 + r;
          storev(&Cg[(size_t)row * ldc + col], acc[mi][ni][r] + bv);
        }
      }
    }
  }
}

// ---------------- Plucker lines ----------------
__device__ __forceinline__ void ext6(float* L, const float* p, const float* q){
  L[0] = p[0]*q[1] - p[1]*q[0];
  L[1] = p[0]*q[2] - p[2]*q[0];
  L[2] = p[0]*q[3] - p[3]*q[0];
  L[3] = p[1]*q[2] - p[2]*q[1];
  L[4] = p[1]*q[3] - p[3]*q[1];
  L[5] = p[2]*q[3] - p[3]*q[2];
  float n = sqrtf(L[0]*L[0]+L[1]*L[1]+L[2]*L[2]+L[3]*L[3]+L[4]*L[4]+L[5]*L[5]);
  float inv = 1.f / fmaxf(n, 1e-12f);
  #pragma unroll
  for (int i = 0; i < 6; i++) L[i] *= inv;
}

// ---------------- fused: chunk+inline-lines [0,256) | powers [256,272) | transpose_v [272,4368) ----------------
__global__ __launch_bounds__(256) void chunk_tv_kernel(const u16* __restrict__ C, const float* __restrict__ Ain,
                                                       float* __restrict__ Sb, u16* __restrict__ VT,
                                                       float* __restrict__ rd, float* __restrict__ Jw,
                                                       float* __restrict__ Gk)
{
  __shared__ float Jl[4][384];
  __shared__ float Af[4][36], Ml[4][36], Nl[4][36];
  __shared__ u16 tile[32][33];
  __shared__ float Pw[36], Cur[36];
  const int blk = blockIdx.x, tid = threadIdx.x;
  if (blk < 256){
    const int g = tid >> 6, lt = tid & 63;
    const int task = blk * 4 + g;           // bh*32 + c
    const int c = task & 31, bh = task >> 5, h = bh & 15, b = bh >> 4;
    // ---- inline lines for t = c*64 + lt ----
    {
      const int t = c * 64 + lt;
      size_t m = (size_t)b * 2048 + t;
      float w1[4] = {0.f, 0.f, 0.f, 0.f}, w2[4], r1[4], r2[4];
      if (t > 0){
        const u16* p2 = C + (m - 1) * LDC + 3072 + h * 4;
        #pragma unroll
        for (int i = 0; i < 4; i++) w1[i] = bf2f(p2[i]);
      }
      {
        const u16* p2 = C + m * LDC + 3136 + h * 4;
        #pragma unroll
        for (int i = 0; i < 4; i++) w2[i] = bf2f(p2[i]);
        p2 = C + m * LDC + 3200 + h * 4;
        #pragma unroll
        for (int i = 0; i < 4; i++) r1[i] = bf2f(p2[i]);
        p2 = C + m * LDC + 3264 + h * 4;
        #pragma unroll
        for (int i = 0; i < 4; i++) r2[i] = bf2f(p2[i]);
      }
      float L[6], R[6];
      ext6(L, w1, w2);
      ext6(R, r1, r2);
      size_t o = ((size_t)bh * 2048 + t) * 6;
      #pragma unroll
      for (int i = 0; i < 6; i++) rd[o + i] = R[i];
      float jv[6] = { L[5], -L[4], L[3], L[2], -L[1], L[0] };   // write_lines @ J6
      #pragma unroll
      for (int i = 0; i < 6; i++){ Jw[o + i] = jv[i]; Jl[g][lt * 6 + i] = jv[i]; }
    }
    const int p = lt / 6, q = lt % 6;
    if (lt < 36){ Af[g][lt] = Ain[h * 36 + lt]; Ml[g][lt] = 0.f; }
    __syncthreads();
    float arow[6], acol[6];
    if (lt < 36){
      #pragma unroll
      for (int k = 0; k < 6; k++){ arow[k] = Af[g][p * 6 + k]; acol[k] = Af[g][q * 6 + k]; }
    }
    for (int s = 0; s < 64; s++){
      float n = 0.f;
      if (lt < 36){
        #pragma unroll
        for (int k = 0; k < 6; k++) n += arow[k] * Ml[g][k * 6 + q];
        Nl[g][lt] = n;
      }
      __syncthreads();
      if (lt < 36){
        float m = Jl[g][s * 6 + p] * Jl[g][s * 6 + q];
        #pragma unroll
        for (int k = 0; k < 6; k++) m += Nl[g][p * 6 + k] * acol[k];
        Ml[g][lt] = m;
      }
      __syncthreads();
    }
    if (lt < 36) Sb[((size_t)bh * 32 + c) * 36 + lt] = Ml[g][lt];
  } else if (blk < 272){
    // ---- powers: Gk[h][k] = A^k, k = 0..64 ----
    const int h = blk - 256;
    const int p = tid / 6, q = tid % 6;
    if (tid < 36){
      Pw[tid] = Ain[h * 36 + tid];
      float id = (p == q) ? 1.f : 0.f;
      Cur[tid] = id;
      Gk[(size_t)h * 65 * 36 + tid] = id;
    }
    __syncthreads();
    for (int k = 1; k <= 64; k++){
      float v = 0.f;
      if (tid < 36){
        #pragma unroll
        for (int j = 0; j < 6; j++) v += Cur[p * 6 + j] * Pw[j * 6 + q];
      }
      __syncthreads();
      if (tid < 36){
        Cur[tid] = v;
        Gk[((size_t)h * 65 + k) * 36 + tid] = v;
      }
      __syncthreads();
    }
  } else {
    // ---- transpose_v ----
    int local = blk - 272;
    int bh = local >> 7, rem = local & 127;
    int b = bh >> 4, h = bh & 15;
    const u16* src = C + (size_t)b * 2048 * LDC + 2048 + h * 64;
    int c0 = (rem & 1) * 32, r0 = (rem >> 1) * 32;
    int tx = tid & 31, ty0 = tid >> 5;
    #pragma unroll
    for (int i = 0; i < 4; i++)
      tile[ty0 + i * 8][tx] = src[(size_t)(r0 + ty0 + i * 8) * LDC + c0 + tx];
    __syncthreads();
    u16* dstb = VT + (size_t)bh * 64 * 2048;
    #pragma unroll
    for (int i = 0; i < 4; i++)
      dstb[(size_t)(c0 + ty0 + i * 8) * 2048 + r0 + tx] = tile[tx][ty0 + i * 8];
  }
}

// ---------------- fused score [0,256) + attention [256,1280) ----------------
// Score blocks dispatch FIRST (overlap attn's shadow). attn: K/V LDS
// double-buffered, one barrier per KV-iter, single-deep register prefetch.
// Q pre-scaled by 0.125*log2(e); defer-max THR=11.5 fast path; T5 setprio.
// score: computes its own boundary prefix B_c from Sb+Gk (<=32 serial steps).
__global__ __launch_bounds__(256) void attn_score_kernel(const u16* __restrict__ C, const u16* __restrict__ VT,
                                                         u16* __restrict__ seqb,
                                                         const float* __restrict__ rd, const float* __restrict__ Jw,
                                                         const float* __restrict__ Gk, const float* __restrict__ Sb,
                                                         float* __restrict__ score)
{
  __shared__ __align__(16) char smem[40960];
  const int blk = blockIdx.x, tid = threadIdx.x;
  if (blk >= 256){
    char* KsB = smem;                        // [2][64][64] swizzled
    char* VsB = smem + 16384;                // [2][64][64]
    const int abk = blk - 256;
    const int bh = abk & 31, bb = bh >> 4, h = bh & 15;
    const int qblk = 31 - (abk >> 5);
    const int lane = tid & 63, w = tid >> 6;
    const int l15 = lane & 15, l4 = lane >> 4;
    u16* Psw = (u16*)(smem + 32768) + w * 1024;   // per-wave [16][64]
    const int q0 = qblk * 64 + w * 16;
    const float csc = 0.1803368801f;   // 0.125 * log2(e)
    const u16* qb = C + (size_t)(bb * 2048 + q0 + l15) * LDC + h * 64 + l4 * 8;
    short8 qf0 = *(const short8*)qb;
    short8 qf1 = *(const short8*)(qb + 32);
    #pragma unroll
    for (int j = 0; j < 8; j++){
      qf0[j] = (short)f2bf(bf2f((u16)qf0[j]) * csc);
      qf1[j] = (short)f2bf(bf2f((u16)qf1[j]) * csc);
    }
    f32x4 o[4] = {};
    float mrun[4], lsum[4];
    #pragma unroll
    for (int r = 0; r < 4; r++){ mrun[r] = -1e30f; lsum[r] = 0.f; }
    const int nkv = qblk + 1;
    const int rowA = tid >> 3, chA = tid & 7;
    const int swA = chA ^ (rowA & 7);
    const u16* Kg = C + (size_t)(bb * 2048) * LDC + 1024 + h * 64 + chA * 8;
    const u16* Vg = VT + ((size_t)bh * 64 + rowA) * 2048 + chA * 8;
    short8 kr0, kr1, vr0, vr1;
    // tile 0 -> regs -> buf0
    kr0 = *(const short8*)(Kg + (size_t)rowA * LDC);
    kr1 = *(const short8*)(Kg + (size_t)(rowA + 32) * LDC);
    vr0 = *(const short8*)(Vg);
    vr1 = *(const short8*)(Vg + 32 * 2048);
    *(short8*)(KsB + rowA * 128 + swA * 16)        = kr0;
    *(short8*)(KsB + (rowA + 32) * 128 + swA * 16) = kr1;
    *(short8*)(VsB + rowA * 128 + swA * 16)        = vr0;
    *(short8*)(VsB + (rowA + 32) * 128 + swA * 16) = vr1;
    if (nkv > 1){   // prefetch tile 1 into regs
      kr0 = *(const short8*)(Kg + (size_t)(64 + rowA) * LDC);
      kr1 = *(const short8*)(Kg + (size_t)(64 + rowA + 32) * LDC);
      vr0 = *(const short8*)(Vg + 64);
      vr1 = *(const short8*)(Vg + 64 + 32 * 2048);
    }
    for (int i = 0; i < nkv; i++){
      const int cur = i & 1;
      __syncthreads();   // buf[cur] writes visible; buf[cur^1] readers (iter i-1) done
      if (i + 1 < nkv){
        char* Kd = KsB + (cur ^ 1) * 8192;
        char* Vd = VsB + (cur ^ 1) * 8192;
        *(short8*)(Kd + rowA * 128 + swA * 16)        = kr0;
        *(short8*)(Kd + (rowA + 32) * 128 + swA * 16) = kr1;
        *(short8*)(Vd + rowA * 128 + swA * 16)        = vr0;
        *(short8*)(Vd + (rowA + 32) * 128 + swA * 16) = vr1;
        if (i + 2 < nkv){   // WAR on regs is safe: ds_write samples at issue
          int nx = (i + 2) * 64;
          kr0 = *(const short8*)(Kg + (size_t)(nx + rowA) * LDC);
          kr1 = *(const short8*)(Kg + (size_t)(nx + rowA + 32) * LDC);
          vr0 = *(const short8*)(Vg + nx);
          vr1 = *(const short8*)(Vg + nx + 32 * 2048);
        }
      }
      const char* Ks = KsB + cur * 8192;
      const char* Vs = VsB + cur * 8192;
      const bool diag = (i == qblk);
      f32x4 s4[4] = {};
      __builtin_amdgcn_s_setprio(1);
      #pragma unroll
      for (int j = 0; j < 4; j++){
        const int srow = j * 16 + l15, rm = srow & 7;
        const char* base = Ks + srow * 128;
        short8 b0 = *(const short8*)(base + ((l4 ^ rm) << 4));
        short8 b1 = *(const short8*)(base + (((4 + l4) ^ rm) << 4));
        mfma16(s4[j], qf0, b0);
        mfma16(s4[j], qf1, b1);
      }
      __builtin_amdgcn_s_setprio(0);
      float ps[4][4], lm[4];
      #pragma unroll
      for (int r = 0; r < 4; r++){
        float v0 = s4[0][r], v1 = s4[1][r], v2 = s4[2][r], v3 = s4[3][r];
        if (diag){
          int qrow = w * 16 + l4 * 4 + r;
          if (l15 > qrow)      v0 = -1e30f;
          if (16 + l15 > qrow) v1 = -1e30f;
          if (32 + l15 > qrow) v2 = -1e30f;
          if (48 + l15 > qrow) v3 = -1e30f;
        }
        lm[r] = fmaxf(fmaxf(v0, v1), fmaxf(v2, v3));   // per-lane max only
        ps[r][0] = v0; ps[r][1] = v1; ps[r][2] = v2; ps[r][3] = v3;
      }
      int ok = (lm[0] <= mrun[0] + 11.5f) && (lm[1] <= mrun[1] + 11.5f)
            && (lm[2] <= mrun[2] + 11.5f) && (lm[3] <= mrun[3] + 11.5f);
      if (!__all(ok)){
        #pragma unroll
        for (int r = 0; r < 4; r++){
          float mx = lm[r];
          mx = fmaxf(mx, __shfl_xor(mx, 1));
          mx = fmaxf(mx, __shfl_xor(mx, 2));
          mx = fmaxf(mx, __shfl_xor(mx, 4));
          mx = fmaxf(mx, __shfl_xor(mx, 8));
          float mnew = fmaxf(mrun[r], mx);
          float sc = EXP2(mrun[r] - mnew);
          mrun[r] = mnew;
          lsum[r] *= sc;
          o[0][r] *= sc; o[1][r] *= sc; o[2][r] *= sc; o[3][r] *= sc;
        }
      }
      #pragma unroll
      for (int r = 0; r < 4; r++){
        float p0 = EXP2(ps[r][0] - mrun[r]);
        float p1 = EXP2(ps[r][1] - mrun[r]);
        float p2 = EXP2(ps[r][2] - mrun[r]);
        float p3 = EXP2(ps[r][3] - mrun[r]);
        lsum[r] += (p0 + p1) + (p2 + p3);
        ps[r][0] = p0; ps[r][1] = p1; ps[r][2] = p2; ps[r][3] = p3;
      }
      char* pw = (char*)Psw;
      const int cb = (l15 & 7) * 2;
      #pragma unroll
      for (int r = 0; r < 4; r++){
        const int prow = l4 * 4 + r, rm = prow & 7;
        char* prb = pw + prow * 128 + cb;
        #pragma unroll
        for (int j = 0; j < 4; j++){
          int cj = (j * 2 + (l15 >> 3)) ^ rm;
          *((u16*)(prb + cj * 16)) = f2bf_rhu(ps[r][j]);
        }
      }
      const int prm = l15 & 7;
      short8 pa0 = *(const short8*)(pw + l15 * 128 + ((l4 ^ prm) << 4));
      short8 pa1 = *(const short8*)(pw + l15 * 128 + (((4 + l4) ^ prm) << 4));
      __builtin_amdgcn_s_setprio(1);
      #pragma unroll
      for (int j = 0; j < 4; j++){
        const int drow = j * 16 + l15, rm = drow & 7;
        const char* vb = Vs + drow * 128;
        short8 b0 = *(const short8*)(vb + ((l4 ^ rm) << 4));
        short8 b1 = *(const short8*)(vb + (((4 + l4) ^ rm) << 4));
        mfma16(o[j], pa0, b0);
        mfma16(o[j], pa1, b1);
      }
      __builtin_amdgcn_s_setprio(0);
    }
    #pragma unroll
    for (int r = 0; r < 4; r++){
      float ls = lsum[r];
      ls += __shfl_xor(ls, 1);
      ls += __shfl_xor(ls, 2);
      ls += __shfl_xor(ls, 4);
      ls += __shfl_xor(ls, 8);
      float inv = 1.f / ls;
      size_t base = (size_t)(bb * 2048 + q0 + l4 * 4 + r) * 1024 + h * 64;
      seqb[base + l15]      = f2bf(o[0][r] * inv);
      seqb[base + 16 + l15] = f2bf(o[1][r] * inv);
      seqb[base + 32 + l15] = f2bf(o[2][r] * inv);
      seqb[base + 48 + l15] = f2bf(o[3][r] * inv);
    }
  } else {
    float* Gl  = (float*)smem;               // [64][36]
    float* Jl  = (float*)(smem + 9216);      // [320][6]
    float* Bl  = (float*)(smem + 16896);     // [4][36]
    float* A64s= (float*)(smem + 17472);     // [36]
    float* Bw  = (float*)(smem + 17664);     // [36]
    float* Nw  = (float*)(smem + 17856);     // [36]
    const int local = blk;
    const int tblk = local & 7, bh = local >> 3, h = bh & 15;
    const int t0 = tblk * 256;
    for (int i = tid; i < 64 * 36; i += 256) Gl[i] = Gk[(size_t)h * 65 * 36 + i];
    {
      int base = t0 * 6 - 384;
      for (int i = tid; i < 1920; i += 256){
        int s6 = base + i;
        Jl[i] = (s6 >= 0) ? Jw[(size_t)bh * (2048 * 6) + s6] : 0.f;
      }
    }
    // ---- inline boundary prefix: B_0 = 0; B_{c+1} = A64 B_c A64^T + S_c ----
    {
      const int p = tid / 6, q = tid % 6;
      if (tid < 36){ A64s[tid] = Gk[((size_t)h * 65 + 64) * 36 + tid]; Bw[tid] = 0.f; }
      __syncthreads();
      float arow[6], acol[6];
      if (tid < 36){
        #pragma unroll
        for (int k = 0; k < 6; k++){ arow[k] = A64s[p * 6 + k]; acol[k] = A64s[q * 6 + k]; }
      }
      const int cEnd = tblk * 4;
      for (int c = 0; c < cEnd + 4; c++){
        if (tid < 36 && c >= cEnd) Bl[(c - cEnd) * 36 + tid] = Bw[tid];
        float n = 0.f;
        if (tid < 36){
          #pragma unroll
          for (int k = 0; k < 6; k++) n += arow[k] * Bw[k * 6 + q];
        }
        __syncthreads();
        if (tid < 36) Nw[tid] = n;
        __syncthreads();
        if (tid < 36){
          float m = Sb[((size_t)bh * 32 + c) * 36 + tid];
          #pragma unroll
          for (int k = 0; k < 6; k++) m += Nw[p * 6 + k] * acol[k];
          Bw[tid] = m;
        }
        __syncthreads();
      }
    }
    __syncthreads();
    float Ar[36];
    #pragma unroll
    for (int i = 0; i < 36; i++) Ar[i] = Gl[36 + i];   // A^1
    const int t = t0 + tid;
    const int cl = tid >> 6;
    const int dlt = tid & 63;
    float rdv[6];
    {
      const float* rp = rd + ((size_t)bh * 2048 + t) * 6;
      #pragma unroll
      for (int q = 0; q < 6; q++) rdv[q] = rp[q];
    }
    const float* g = Gl + dlt * 36;
    float u[6];
    #pragma unroll
    for (int p = 0; p < 6; p++){
      float s = 0.f;
      #pragma unroll
      for (int q = 0; q < 6; q++) s += rdv[q] * g[q * 6 + p];
      u[p] = s;
    }
    float acc = 0.f;
    #pragma unroll
    for (int p = 0; p < 6; p++){
      float bv = 0.f;
      #pragma unroll
      for (int q = 0; q < 6; q++) bv += Bl[cl * 36 + p * 6 + q] * u[q];
      acc += u[p] * bv;
    }
    float wv[6];
    #pragma unroll
    for (int q = 0; q < 6; q++) wv[q] = rdv[q];
    const int sIdx = tid + 63;
    for (int k = 0; k < dlt; k++){
      const float* jp = Jl + (sIdx - k) * 6;
      float uu = wv[0]*jp[0] + wv[1]*jp[1] + wv[2]*jp[2] + wv[3]*jp[3] + wv[4]*jp[4] + wv[5]*jp[5];
      acc += uu * uu;
      float nw[6];
      #pragma unroll
      for (int q = 0; q < 6; q++)
        nw[q] = wv[0]*Ar[q] + wv[1]*Ar[6+q] + wv[2]*Ar[12+q] + wv[3]*Ar[18+q] + wv[4]*Ar[24+q] + wv[5]*Ar[30+q];
      #pragma unroll
      for (int q = 0; q < 6; q++) wv[q] = nw[q];
    }
    score[(size_t)bh * 2048 + t] = acc;
  }
}

// ---------------- fused gated mean + combine ----------------
// 32 lanes (2 rows x 16 heads) compute the gate products in parallel,
// 16-lane shuffle reduce.
__global__ __launch_bounds__(256) void gated_combine_kernel(const float* __restrict__ score, const u16* __restrict__ C,
                                                            const float* __restrict__ mem_scale,
                                                            const u16* __restrict__ seqb, u16* __restrict__ preb)
{
  __shared__ float gsh[2];
  const int blk = blockIdx.x, tid = threadIdx.x;
  const int m0 = blk * 2;
  if (tid < 32){
    const int mm = tid >> 4, h2 = tid & 15;
    const int m = m0 + mm;
    const int b = m >> 11, t = m & 2047;
    float sc = score[(size_t)(b * 16 + h2) * 2048 + t];
    float v = sigm(sc * mem_scale[h2]) * sigm(bf2f(C[(size_t)m * LDC + 4352 + h2]));
    v += __shfl_xor(v, 1);
    v += __shfl_xor(v, 2);
    v += __shfl_xor(v, 4);
    v += __shfl_xor(v, 8);
    if (h2 == 0) gsh[mm] = v * (1.f / 16.f);
  }
  __syncthreads();
  const int m = m0 + (tid >> 7), d8 = (tid & 127) * 8;
  const float g = gsh[tid >> 7];
  short8 sv = *(const short8*)(seqb + (size_t)m * 1024 + d8);
  short8 mv = *(const short8*)(C + (size_t)m * LDC + 3328 + d8);
  short8 ov;
  #pragma unroll
  for (int j = 0; j < 8; j++){
    float f = bf2f((u16)sv[j]) + g * bf2f((u16)mv[j]);
    ov[j] = (short)f2bf(f);
  }
  *(short8*)(preb + (size_t)m * 1024 + d8) = ov;
}

// ---------------- launcher ----------------
extern "C" void kernel_launch(void* const* d_in, const int* in_sizes, int n_in,
                              void* d_out, int out_size, void* d_ws, size_t ws_size,
                              hipStream_t stream)
{
  (void)in_sizes; (void)n_in; (void)out_size; (void)ws_size;
  const float* x     = (const float*)d_in[0];
  const float* Wqkv  = (const float*)d_in[1];
  const float* bqkv  = (const float*)d_in[2];
  const float* W1w   = (const float*)d_in[3];
  const float* W2w   = (const float*)d_in[4];
  const float* W1r   = (const float*)d_in[5];
  const float* W2r   = (const float*)d_in[6];
  const float* Wmv   = (const float*)d_in[7];
  const float* bmv   = (const float*)d_in[8];
  const float* Wg    = (const float*)d_in[9];
  const float* bg    = (const float*)d_in[10];
  const float* mem_scale = (const float*)d_in[11];
  const float* Wout  = (const float*)d_in[12];
  const float* bout  = (const float*)d_in[13];
  const float* Am    = (const float*)d_in[14];
  float* out = (float*)d_out;

  char* p = (char*)d_ws;
  auto carve = [&](size_t bytes) -> void* {
    void* r = (void*)p;
    p += (bytes + 255) & ~(size_t)255;
    return r;
  };
  u16*   xb       = (u16*)  carve((size_t)4096 * 1024 * 2);
  u16*   C        = (u16*)  carve((size_t)4096 * LDC * 2);
  u16*   BT       = (u16*)  carve((size_t)LDC * 1024 * 2);
  u16*   WoutT    = (u16*)  carve((size_t)1024 * 1024 * 2);
  float* biasfull = (float*)carve((size_t)LDC * 4);
  u16*   VTb      = (u16*)  carve((size_t)32 * 64 * 2048 * 2);
  u16*   seqb     = (u16*)  carve((size_t)4096 * 1024 * 2);
  float* rdb      = (float*)carve((size_t)32 * 2048 * 6 * 4);
  float* Jwb      = (float*)carve((size_t)32 * 2048 * 6 * 4);
  float* Gk       = (float*)carve((size_t)16 * 65 * 36 * 4);
  float* Sbb      = (float*)carve((size_t)32 * 32 * 36 * 4);
  float* scoreb   = (float*)carve((size_t)32 * 2048 * 4);
  u16*   preb     = (u16*)  carve((size_t)4096 * 1024 * 2);

  prep_kernel<<<7474, 256, 0, stream>>>(x, bqkv, bmv, bg, Wqkv, W1w, W2w, W1r, W2r,
                                        Wmv, Wout, Wg, xb, biasfull, BT, WoutT);

  // fused projection GEMM (grid 1120 = 32 x 35, BN=128)
  gemm_bt<u16, 128><<<1120, 256, 0, stream>>>(xb, BT, biasfull, C, 4096, LDC, 1024, LDC);

  // chunk(+inline lines) | powers | transpose_v
  chunk_tv_kernel<<<4368, 256, 0, stream>>>(C, Am, Sbb, VTb, rdb, Jwb, Gk);

  // score (first, overlaps attn) + attention
  attn_score_kernel<<<1280, 256, 0, stream>>>(C, VTb, seqb, rdb, Jwb, Gk, Sbb, scoreb);

  gated_combine_kernel<<<2048, 256, 0, stream>>>(scoreb, C, mem_scale, seqb, preb);

  // final GEMM: out = pre @ Wout + bout (f32 out, BN=64 -> grid 512 = 2 blocks/CU)
  gemm_bt<float, 64><<<512, 256, 0, stream>>>(preb, WoutT, bout, out, 4096, 1024, 1024, 1024);
}